// Round 6
// baseline (423.362 us; speedup 1.0000x reference)
//
#include <hip/hip_runtime.h>
#include <math.h>

#define B_ 64
#define S_ 64
#define U_ 16
#define EMB_ 10
#define D_ 34
#define DD_ 3
#define FF_ 4
#define NL_ 4

typedef float v2f __attribute__((ext_vector_type(2)));

// ---------------------------------------------------------------------------
// Kernel A: encoder — EXACT R13 (measured best: total 336.2 µs, enc ~63.7).
// FROZEN.
// ---------------------------------------------------------------------------
__global__ __launch_bounds__(512) void enc_kernel(
    const float* __restrict__ src, const float* __restrict__ wemb,
    const float* __restrict__ semb,
    const float* __restrict__ qkv_w, const float* __restrict__ qkv_b,
    const float* __restrict__ out_w, const float* __restrict__ out_b,
    const float* __restrict__ ln1_w, const float* __restrict__ ln1_b,
    const float* __restrict__ lin1_w, const float* __restrict__ lin1_b,
    const float* __restrict__ lin2_w, const float* __restrict__ lin2_b,
    const float* __restrict__ ln2_w, const float* __restrict__ ln2_b,
    const float* __restrict__ norm_w, const float* __restrict__ norm_b,
    const float* __restrict__ eo_w, const float* __restrict__ eo_b,
    float* __restrict__ mem, float* __restrict__ out)
{
    const int b = blockIdx.x;
    const int tid = threadIdx.x;
    const int wv_ = tid >> 6;
    const int lane = tid & 63;

    __shared__ float xs[S_][D_ + 1];
    __shared__ float tmp[S_][D_ + 1];
    __shared__ float att[S_][D_ + 1];
    __shared__ __align__(16) float qsh[2][S_][21];
    __shared__ __align__(16) float ksh[2][S_][20];
    __shared__ __align__(16) float vsh[2][S_][20];
    __shared__ float ffh[S_][5];
    __shared__ float pacc[4][128][19];

    const float rs17 = 0.24253562503633297f;
    const float negln = -logf(10000.0f) / (float)D_;

    // ---- embed + positional encoding
    #pragma unroll
    for (int rr = 0; rr < 5; ++rr) {
        int idx = tid + rr * 512;
        if (idx < S_ * D_) {
            int pos = idx / D_, d = idx % D_;
            float v;
            if (d < U_ - 2) {
                v = src[(b * S_ + pos) * U_ + d];
            } else if (d < U_ - 2 + EMB_) {
                int wi = (int)src[(b * S_ + pos) * U_ + (U_ - 2)];
                v = wemb[wi * EMB_ + (d - (U_ - 2))];
            } else {
                int si = (int)src[(b * S_ + pos) * U_ + (U_ - 1)];
                v = semb[si * EMB_ + (d - (U_ - 2 + EMB_))];
            }
            int k = d >> 1;
            float div = __expf((float)(2 * k) * negln);
            float ang = (float)b * div;
            v += (d & 1) ? __cosf(ang) : __sinf(ang);
            xs[pos][d] = v;
        }
    }
    __syncthreads();

    for (int l = 0; l < NL_; ++l) {
        const float* Wq = qkv_w + l * 3 * D_ * D_;
        const float* Bq = qkv_b + l * 3 * D_;

        // ---- qkv: lane = pos; wave owns rows r = wv_ + 8k; pk_fma dot
        {
            v2f xr2[17];
            #pragma unroll
            for (int d2 = 0; d2 < 17; ++d2) {
                v2f t; t.x = xs[lane][2 * d2]; t.y = xs[lane][2 * d2 + 1];
                xr2[d2] = t;
            }
            #pragma unroll
            for (int rb = 0; rb < 13; ++rb) {
                int r = wv_ + (rb << 3);
                if (r < 3 * D_) {
                    int ru = __builtin_amdgcn_readfirstlane(r);
                    const v2f* w2 = (const v2f*)(Wq + ru * D_);
                    v2f a2; a2.x = Bq[ru]; a2.y = 0.f;
                    #pragma unroll
                    for (int d2 = 0; d2 < 17; ++d2)
                        a2 = __builtin_elementwise_fma(xr2[d2], w2[d2], a2);
                    float acc = a2.x + a2.y;
                    if (ru < D_)          { int h = (ru >= 17), dd = ru - h * 17; qsh[h][lane][dd] = acc; }
                    else if (ru < 2 * D_) { int rr2 = ru - D_;     int h = (rr2 >= 17), dd = rr2 - h * 17; ksh[h][lane][dd] = acc; }
                    else                  { int rr2 = ru - 2 * D_; int h = (rr2 >= 17), dd = rr2 - h * 17; vsh[h][lane][dd] = acc; }
                }
            }
        }
        __syncthreads();

        // ---- attention, 4-way key-parallel
        {
            int c = tid >> 7, hq = tid & 127;
            int h = hq >> 6, qi = hq & 63;
            float qv[17], acc[17];
            #pragma unroll
            for (int d = 0; d < 17; ++d) { qv[d] = qsh[h][qi][d]; acc[d] = 0.f; }
            float ssum = 0.f;
            int j0 = c * 16;
            #pragma unroll 4
            for (int jj = 0; jj < 16; ++jj) {
                int j = j0 + jj;
                const float4* kr = (const float4*)ksh[h][j];
                const float4* vr = (const float4*)vsh[h][j];
                float4 k0 = kr[0], k1 = kr[1], k2 = kr[2], k3 = kr[3];
                float  k16 = ksh[h][j][16];
                float4 v0 = vr[0], v1 = vr[1], v2 = vr[2], v3 = vr[3];
                float  v16 = vsh[h][j][16];
                float sE = qv[0]*k0.x + qv[2]*k0.z + qv[4]*k1.x + qv[6]*k1.z +
                           qv[8]*k2.x + qv[10]*k2.z + qv[12]*k3.x + qv[14]*k3.z;
                float sO = qv[1]*k0.y + qv[3]*k0.w + qv[5]*k1.y + qv[7]*k1.w +
                           qv[9]*k2.y + qv[11]*k2.w + qv[13]*k3.y + qv[15]*k3.w;
                float sc = sE + sO + qv[16]*k16;
                float e = __expf(sc * rs17);
                ssum += e;
                acc[0] += e*v0.x;  acc[1] += e*v0.y;  acc[2] += e*v0.z;  acc[3] += e*v0.w;
                acc[4] += e*v1.x;  acc[5] += e*v1.y;  acc[6] += e*v1.z;  acc[7] += e*v1.w;
                acc[8] += e*v2.x;  acc[9] += e*v2.y;  acc[10] += e*v2.z; acc[11] += e*v2.w;
                acc[12] += e*v3.x; acc[13] += e*v3.y; acc[14] += e*v3.z; acc[15] += e*v3.w;
                acc[16] += e*v16;
            }
            #pragma unroll
            for (int d = 0; d < 17; ++d) pacc[c][hq][d] = acc[d];
            pacc[c][hq][17] = ssum;
        }
        __syncthreads();

        if (tid < 128) {
            int h = tid >> 6, qi = tid & 63;
            int off = h * 17;
            float ssum = pacc[0][tid][17] + pacc[1][tid][17] +
                         pacc[2][tid][17] + pacc[3][tid][17];
            float inv = 1.f / ssum;
            #pragma unroll
            for (int d = 0; d < 17; ++d)
                att[qi][off + d] = (pacc[0][tid][d] + pacc[1][tid][d] +
                                    pacc[2][tid][d] + pacc[3][tid][d]) * inv;
        }
        __syncthreads();

        // ---- out proj + residual (pk_fma)
        {
            v2f ar2[17];
            #pragma unroll
            for (int d2 = 0; d2 < 17; ++d2) {
                v2f t; t.x = att[lane][2 * d2]; t.y = att[lane][2 * d2 + 1];
                ar2[d2] = t;
            }
            const float* Wo = out_w + l * D_ * D_;
            const float* Bo = out_b + l * D_;
            #pragma unroll
            for (int rb = 0; rb < 5; ++rb) {
                int d = wv_ + (rb << 3);
                if (d < D_) {
                    int du = __builtin_amdgcn_readfirstlane(d);
                    const v2f* w2 = (const v2f*)(Wo + du * D_);
                    v2f a2; a2.x = Bo[du]; a2.y = 0.f;
                    #pragma unroll
                    for (int d2 = 0; d2 < 17; ++d2)
                        a2 = __builtin_elementwise_fma(ar2[d2], w2[d2], a2);
                    tmp[lane][du] = xs[lane][du] + a2.x + a2.y;
                }
            }
        }
        __syncthreads();

        // ---- LN1: 8 threads/row (all 512 active), shfl_xor(8) reduction
        {
            int row = tid >> 3, sub = tid & 7;
            float s = 0.f, sq = 0.f;
            #pragma unroll
            for (int d = sub; d < D_; d += 8) { float t = tmp[row][d]; s += t; sq = fmaf(t, t, sq); }
            #pragma unroll
            for (int m = 1; m < 8; m <<= 1) { s += __shfl_xor(s, m, 8); sq += __shfl_xor(sq, m, 8); }
            float mu = s * (1.0f / D_);
            float var = fmaf(sq, 1.0f / D_, -mu * mu);
            float rstd = rsqrtf(var + 1e-5f);
            #pragma unroll
            for (int d = sub; d < D_; d += 8)
                xs[row][d] = (tmp[row][d] - mu) * rstd * ln1_w[l * D_ + d] + ln1_b[l * D_ + d];
        }
        __syncthreads();

        // ---- FF1 (34 -> 4, relu): waves 0..3 (pk_fma)
        if (wv_ < 4) {
            int fu = __builtin_amdgcn_readfirstlane(wv_);
            const v2f* w2 = (const v2f*)(lin1_w + l * FF_ * D_ + fu * D_);
            v2f a2; a2.x = lin1_b[l * FF_ + fu]; a2.y = 0.f;
            #pragma unroll
            for (int d2 = 0; d2 < 17; ++d2) {
                v2f t; t.x = xs[lane][2 * d2]; t.y = xs[lane][2 * d2 + 1];
                a2 = __builtin_elementwise_fma(t, w2[d2], a2);
            }
            ffh[lane][fu] = fmaxf(a2.x + a2.y, 0.f);
        }
        __syncthreads();

        // ---- FF2 (4 -> 34) + residual
        {
            float h0 = ffh[lane][0], h1 = ffh[lane][1],
                  h2 = ffh[lane][2], h3 = ffh[lane][3];
            const float* W2 = lin2_w + l * D_ * FF_;
            const float* B2 = lin2_b + l * D_;
            #pragma unroll
            for (int rb = 0; rb < 5; ++rb) {
                int d = wv_ + (rb << 3);
                if (d < D_) {
                    int du = __builtin_amdgcn_readfirstlane(d);
                    const float* wrow = W2 + du * FF_;
                    float acc = fmaf(h0, wrow[0], fmaf(h1, wrow[1],
                                fmaf(h2, wrow[2], fmaf(h3, wrow[3], B2[du]))));
                    tmp[lane][du] = xs[lane][du] + acc;
                }
            }
        }
        __syncthreads();

        // ---- LN2: 8 threads/row
        {
            int row = tid >> 3, sub = tid & 7;
            float s = 0.f, sq = 0.f;
            #pragma unroll
            for (int d = sub; d < D_; d += 8) { float t = tmp[row][d]; s += t; sq = fmaf(t, t, sq); }
            #pragma unroll
            for (int m = 1; m < 8; m <<= 1) { s += __shfl_xor(s, m, 8); sq += __shfl_xor(sq, m, 8); }
            float mu = s * (1.0f / D_);
            float var = fmaf(sq, 1.0f / D_, -mu * mu);
            float rstd = rsqrtf(var + 1e-5f);
            #pragma unroll
            for (int d = sub; d < D_; d += 8)
                xs[row][d] = (tmp[row][d] - mu) * rstd * ln2_w[l * D_ + d] + ln2_b[l * D_ + d];
        }
        __syncthreads();
    }

    // ---- final LayerNorm: 8 threads/row
    {
        int row = tid >> 3, sub = tid & 7;
        float s = 0.f, sq = 0.f;
        #pragma unroll
        for (int d = sub; d < D_; d += 8) { float t = xs[row][d]; s += t; sq = fmaf(t, t, sq); }
        #pragma unroll
        for (int m = 1; m < 8; m <<= 1) { s += __shfl_xor(s, m, 8); sq += __shfl_xor(sq, m, 8); }
        float mu = s * (1.0f / D_);
        float var = fmaf(sq, 1.0f / D_, -mu * mu);
        float rstd = rsqrtf(var + 1e-5f);
        #pragma unroll
        for (int d = sub; d < D_; d += 8)
            tmp[row][d] = (xs[row][d] - mu) * rstd * norm_w[d] + norm_b[d];
    }
    __syncthreads();

    // ---- memory = x @ eo_w.T + eo_b : waves 0..2 (pk_fma), reads tmp
    if (wv_ < 3) {
        int ru = __builtin_amdgcn_readfirstlane(wv_);
        const v2f* w2 = (const v2f*)(eo_w + ru * D_);
        v2f a2; a2.x = eo_b[ru]; a2.y = 0.f;
        #pragma unroll
        for (int d2 = 0; d2 < 17; ++d2) {
            v2f t; t.x = tmp[lane][2 * d2]; t.y = tmp[lane][2 * d2 + 1];
            a2 = __builtin_elementwise_fma(t, w2[d2], a2);
        }
        mem[(b * S_ + lane) * DD_ + ru] = a2.x + a2.y;
    }

    if (tid < S_) {
        out[(b * S_ + tid) * 5 + 3] = src[(b * S_ + tid) * U_ + (U_ - 2)];
        out[(b * S_ + tid) * 5 + 4] = src[(b * S_ + tid) * U_ + (U_ - 1)];
    }
}

// ---------------------------------------------------------------------------
// Kernel B: decoder — R20. SIMT-batching: 4 batches per wave, one per 16-lane
// group (grp = lane>>4). R19 showed issue-bound (VALUBusy ~73% of active-SIMD
// ceiling); every scalar-chain instruction now serves 4 batches (per-lane y).
// Attention positions: 4 slots/lane (slot s = position s*16 + (lane&15));
// reductions: 4-stage all-lane-in-16 DPP butterfly (xor1, xor2,
// row_half_mirror, row_mirror) — no readlane, no cross-16 op, single i-loop.
// KV update: lane-match exec + 4-way UNIFORM branch on i>>4 (static slot
// indexing, no scratch). Carries R16/R19's LN folds + scale-invariance.
// ---------------------------------------------------------------------------
#define PIN(x) asm volatile("" : "+v"(x))

template <int CTRL>
__device__ __forceinline__ void dpp4(float& a, float& b, float& c, float& d) {
    int ta = __builtin_amdgcn_update_dpp(0, __float_as_int(a), CTRL, 0xf, 0xf, true);
    int tb = __builtin_amdgcn_update_dpp(0, __float_as_int(b), CTRL, 0xf, 0xf, true);
    int tc = __builtin_amdgcn_update_dpp(0, __float_as_int(c), CTRL, 0xf, 0xf, true);
    int td = __builtin_amdgcn_update_dpp(0, __float_as_int(d), CTRL, 0xf, 0xf, true);
    a += __int_as_float(ta);
    b += __int_as_float(tb);
    c += __int_as_float(tc);
    d += __int_as_float(td);
}

// Sum within each 16-lane group; result lands in EVERY lane of the group.
// xor1/xor2 via quad_perm; then mirror-based stages (valid because values are
// uniform within 4- and 8-subblocks by the time each mirror runs).
__device__ __forceinline__ void hsum16_4(float& a, float& b, float& c, float& d) {
    dpp4<0xB1>(a, b, c, d);    // quad_perm [1,0,3,2] : xor 1
    dpp4<0x4E>(a, b, c, d);    // quad_perm [2,3,0,1] : xor 2
    dpp4<0x141>(a, b, c, d);   // row_half_mirror    : swap 4-blocks within 8
    dpp4<0x140>(a, b, c, d);   // row_mirror         : swap 8-blocks within 16
}

__device__ __forceinline__ void ln3e(float z0, float z1, float z2,
                                     float w0, float w1, float w2,
                                     float b0, float b1, float b2,
                                     float& o0, float& o1, float& o2) {
    float s1 = (z0 + z1) + z2;
    float s2 = fmaf(z0, z0, fmaf(z1, z1, z2 * z2));
    float mu = s1 * (1.0f / 3.0f);
    float vpe = fmaf(s2, (1.0f / 3.0f), fmaf(-mu, mu, 1e-5f));
    float rstd = __builtin_amdgcn_rsqf(vpe);
    o0 = fmaf(z0 - mu, rstd * w0, b0);
    o1 = fmaf(z1 - mu, rstd * w1, b1);
    o2 = fmaf(z2 - mu, rstd * w2, b2);
}

__global__ __launch_bounds__(64, 1) void dec_kernel(
    const float* __restrict__ mem,
    const float* __restrict__ sa_qkv_w, const float* __restrict__ sa_qkv_b,
    const float* __restrict__ sa_out_w, const float* __restrict__ sa_out_b,
    const float* __restrict__ gln1_w, const float* __restrict__ gln1_b,
    const float* __restrict__ ca_qkv_w, const float* __restrict__ ca_qkv_b,
    const float* __restrict__ ca_out_w, const float* __restrict__ ca_out_b,
    const float* __restrict__ gln2_w, const float* __restrict__ gln2_b,
    const float* __restrict__ l1_w, const float* __restrict__ l1_b,
    const float* __restrict__ l2_w, const float* __restrict__ l2_b,
    const float* __restrict__ gln3_w, const float* __restrict__ gln3_b,
    float* __restrict__ out)
{
    const int b0 = blockIdx.x * 4;
    const int lane = threadIdx.x;
    const int grp = lane >> 4, j16 = lane & 15;
    const int bb = b0 + grp;
    const float LOG2E = 1.4426950408889634f;
    const float rs3 = 0.5773502691896258f;
    const float QS = rs3 * LOG2E;   // score scale folded into weights, exp->exp2

    // ---- FF-tail weight stage: W1N = W1 ∘ N2w, b1n = W1·N2b + b1 (LN2 fold)
    __shared__ __align__(16) float fst[NL_][40];
    for (int t = lane; t < NL_ * 40; t += 64) {
        int l = t / 40, s = t % 40;
        float v = 0.f;
        if      (s < 12) v = l1_w[l * 12 + s] * gln2_w[l * 3 + (s % 3)];
        else if (s < 16) {
            int j = s - 12;
            v = l1_w[l * 12 + j * 3 + 0] * gln2_b[l * 3 + 0] +
                l1_w[l * 12 + j * 3 + 1] * gln2_b[l * 3 + 1] +
                l1_w[l * 12 + j * 3 + 2] * gln2_b[l * 3 + 2] + l1_b[l * 4 + j];
        }
        else if (s < 28) v = l2_w[l * 12 + (s - 16)];
        else if (s < 31) v = l2_b[l * 3 + (s - 28)];
        else if (s < 34) v = gln3_w[l * 3 + (s - 31)];
        else if (s < 37) v = gln3_b[l * 3 + (s - 34)];
        fst[l][s] = v;
    }
    __syncthreads();

    // ---- shared persistent weights (same for all batches)
    float Wsq[NL_][9][3], Bsq[NL_][9];
    float Wso[NL_][3][3], Bso[NL_][3];
    float N1w[NL_][3], N1b[NL_][3];
    float N2w[NL_][3], N2b[NL_][3];
    float Bco[NL_][3];
    // per-lane-per-slot folded cross-attn constants (4 memory positions/lane)
    float wcu[4][NL_][3];
    float swcu[4][NL_];
    float cbb[4][NL_];
    float cvp[4][NL_][3];

    #pragma unroll
    for (int l = 0; l < NL_; ++l) {
        #pragma unroll
        for (int r = 0; r < 9; ++r) {
            float sc = (r < 3) ? QS : 1.0f;
            Bsq[l][r] = sa_qkv_b[l * 9 + r] * sc;
            #pragma unroll
            for (int c = 0; c < 3; ++c) Wsq[l][r][c] = sa_qkv_w[l * 27 + r * 3 + c] * sc;
        }
        #pragma unroll
        for (int r = 0; r < 3; ++r) {
            Bso[l][r] = sa_out_b[l * 3 + r];
            Bco[l][r] = ca_out_b[l * 3 + r];
            N1w[l][r] = gln1_w[l * 3 + r];  N1b[l][r] = gln1_b[l * 3 + r];
            N2w[l][r] = gln2_w[l * 3 + r];  N2b[l][r] = gln2_b[l * 3 + r];
            #pragma unroll
            for (int c = 0; c < 3; ++c) Wso[l][r][c] = sa_out_w[l * 9 + r * 3 + c];
        }
    }

    // ---- per-slot cross-attn K/V + query-side folds (LN1 folded in)
    #pragma unroll
    for (int s4 = 0; s4 < 4; ++s4) {
        float m0 = mem[(bb * S_ + s4 * 16 + j16) * DD_ + 0];
        float m1 = mem[(bb * S_ + s4 * 16 + j16) * DD_ + 1];
        float m2 = mem[(bb * S_ + s4 * 16 + j16) * DD_ + 2];
        #pragma unroll
        for (int l = 0; l < NL_; ++l) {
            float ck[3], cv[3], cuv[3];
            #pragma unroll
            for (int r = 0; r < 3; ++r) {
                ck[r] = ca_qkv_w[l * 27 + (3 + r) * 3 + 0] * m0 +
                        ca_qkv_w[l * 27 + (3 + r) * 3 + 1] * m1 +
                        ca_qkv_w[l * 27 + (3 + r) * 3 + 2] * m2 + ca_qkv_b[l * 9 + 3 + r];
                cv[r] = ca_qkv_w[l * 27 + (6 + r) * 3 + 0] * m0 +
                        ca_qkv_w[l * 27 + (6 + r) * 3 + 1] * m1 +
                        ca_qkv_w[l * 27 + (6 + r) * 3 + 2] * m2 + ca_qkv_b[l * 9 + 6 + r];
            }
            #pragma unroll
            for (int s = 0; s < 3; ++s)
                cuv[s] = QS * (ca_qkv_w[l * 27 + 0 + s] * ck[0] +
                               ca_qkv_w[l * 27 + 3 + s] * ck[1] +
                               ca_qkv_w[l * 27 + 6 + s] * ck[2]);
            float cbv = QS * (ca_qkv_b[l * 9 + 0] * ck[0] +
                              ca_qkv_b[l * 9 + 1] * ck[1] +
                              ca_qkv_b[l * 9 + 2] * ck[2]);
            #pragma unroll
            for (int r = 0; r < 3; ++r)
                cvp[s4][l][r] = ca_out_w[l * 9 + r * 3 + 0] * cv[0] +
                                ca_out_w[l * 9 + r * 3 + 1] * cv[1] +
                                ca_out_w[l * 9 + r * 3 + 2] * cv[2];
            #pragma unroll
            for (int r = 0; r < 3; ++r) wcu[s4][l][r] = cuv[r] * N1w[l][r];
            swcu[s4][l] = wcu[s4][l][0] + wcu[s4][l][1] + wcu[s4][l][2];
            cbb[s4][l]  = cbv + cuv[0] * N1b[l][0] + cuv[1] * N1b[l][1] + cuv[2] * N1b[l][2];
        }
    }

    // ---- pin the chain-critical persistent set
    #pragma unroll
    for (int l = 0; l < NL_; ++l) {
        #pragma unroll
        for (int r = 0; r < 9; ++r) {
            PIN(Bsq[l][r]);
            #pragma unroll
            for (int c = 0; c < 3; ++c) PIN(Wsq[l][r][c]);
        }
        #pragma unroll
        for (int r = 0; r < 3; ++r) {
            PIN(Bso[l][r]); PIN(Bco[l][r]);
            PIN(N1w[l][r]); PIN(N1b[l][r]); PIN(N2w[l][r]); PIN(N2b[l][r]);
            #pragma unroll
            for (int c = 0; c < 3; ++c) PIN(Wso[l][r][c]);
        }
        #pragma unroll
        for (int s4 = 0; s4 < 4; ++s4) {
            PIN(swcu[s4][l]); PIN(cbb[s4][l]);
            #pragma unroll
            for (int r = 0; r < 3; ++r) { PIN(wcu[s4][l][r]); PIN(cvp[s4][l][r]); }
        }
    }

    // self-attn KV cache: slot s holds position s*16 + j16 of this group's batch
    float sk[4][NL_][3] = {{{0.f}}}, sv[4][NL_][3] = {{{0.f}}};

    if (j16 < 3) out[(bb * S_ + 0) * 5 + j16] = 0.f;

    float y0 = 0.f, y1 = 0.f, y2 = 0.f;

    for (int i = 0; i < S_ - 1; ++i) {
        // causal masks per slot (position s*16 + j16 <= i), once per step
        float msa[4];
        #pragma unroll
        for (int s = 0; s < 4; ++s)
            msa[s] = (s * 16 + j16 <= i) ? 0.f : -1.0e30f;
        bool lm = (j16 == (i & 15));

        #pragma unroll
        for (int l = 0; l < NL_; ++l) {
            // ---- FF-tail weights: ds_reads issued at layer top, PINned late
            float wv[40];
            {
                const float4* fp = (const float4*)fst[l];
                #pragma unroll
                for (int k = 0; k < 10; ++k) {
                    float4 t4 = fp[k];
                    wv[4 * k + 0] = t4.x; wv[4 * k + 1] = t4.y;
                    wv[4 * k + 2] = t4.z; wv[4 * k + 3] = t4.w;
                }
            }

            // ---- causal self-attention (q pre-scaled by QS)
            float q[3], kn[3], vn[3], vp[3];
            #pragma unroll
            for (int r = 0; r < 3; ++r) {
                kn[r] = fmaf(Wsq[l][3 + r][0], y0, fmaf(Wsq[l][3 + r][1], y1, fmaf(Wsq[l][3 + r][2], y2, Bsq[l][3 + r])));
                q[r]  = fmaf(Wsq[l][r][0], y0, fmaf(Wsq[l][r][1], y1, fmaf(Wsq[l][r][2], y2, Bsq[l][r])));
                vn[r] = fmaf(Wsq[l][6 + r][0], y0, fmaf(Wsq[l][6 + r][1], y1, fmaf(Wsq[l][6 + r][2], y2, Bsq[l][6 + r])));
            }
            // out-projection folded into the value (off the critical path)
            #pragma unroll
            for (int r = 0; r < 3; ++r)
                vp[r] = fmaf(Wso[l][r][0], vn[0], fmaf(Wso[l][r][1], vn[1], Wso[l][r][2] * vn[2]));
            // KV write: lane-match exec mask + uniform slot branch (static idx)
            if (lm) {
                if (i < 16) {
                    #pragma unroll
                    for (int r = 0; r < 3; ++r) { sk[0][l][r] = kn[r]; sv[0][l][r] = vp[r]; }
                } else if (i < 32) {
                    #pragma unroll
                    for (int r = 0; r < 3; ++r) { sk[1][l][r] = kn[r]; sv[1][l][r] = vp[r]; }
                } else if (i < 48) {
                    #pragma unroll
                    for (int r = 0; r < 3; ++r) { sk[2][l][r] = kn[r]; sv[2][l][r] = vp[r]; }
                } else {
                    #pragma unroll
                    for (int r = 0; r < 3; ++r) { sk[3][l][r] = kn[r]; sv[3][l][r] = vp[r]; }
                }
            }
            // scores + exp per slot
            float e_[4];
            #pragma unroll
            for (int s = 0; s < 4; ++s) {
                float sc = fmaf(q[0], sk[s][l][0], fmaf(q[1], sk[s][l][1], fmaf(q[2], sk[s][l][2], msa[s])));
                e_[s] = __builtin_amdgcn_exp2f(sc);
            }
            float se = (e_[0] + e_[1]) + (e_[2] + e_[3]);
            float S0 = fmaf(e_[3], sv[3][l][0], fmaf(e_[2], sv[2][l][0], fmaf(e_[1], sv[1][l][0], e_[0] * sv[0][l][0])));
            float S1 = fmaf(e_[3], sv[3][l][1], fmaf(e_[2], sv[2][l][1], fmaf(e_[1], sv[1][l][1], e_[0] * sv[0][l][1])));
            float S2 = fmaf(e_[3], sv[3][l][2], fmaf(e_[2], sv[2][l][2], fmaf(e_[1], sv[1][l][2], e_[0] * sv[0][l][2])));
            hsum16_4(se, S0, S1, S2);
            // scale-invariant LN input: z = yb*es + S (no rcp on chain)
            float yb0 = y0 + Bso[l][0], yb1 = y1 + Bso[l][1], yb2 = y2 + Bso[l][2];
            float z0 = fmaf(yb0, se, S0), z1 = fmaf(yb1, se, S1), z2v = fmaf(yb2, se, S2);
            float ee = se * se;

            // ---- LN1 + folded CA scores per slot (rstd on chain; y1 off-chain)
            float s1m = (z0 + z1) + z2v;
            float mu = s1m * (1.0f / 3.0f);
            float s2m = fmaf(z0, z0, fmaf(z1, z1, z2v * z2v));
            float vpe = fmaf(s2m, (1.0f / 3.0f), fmaf(-mu, mu, 1e-5f * ee));
            float rstd1 = __builtin_amdgcn_rsqf(vpe);
            float e2_[4];
            #pragma unroll
            for (int s = 0; s < 4; ++s) {
                float zw = fmaf(z0, wcu[s][l][0], fmaf(z1, wcu[s][l][1], z2v * wcu[s][l][2]));
                float inner = fmaf(-mu, swcu[s][l], zw);
                float sc2 = fmaf(rstd1, inner, cbb[s][l]);
                e2_[s] = __builtin_amdgcn_exp2f(sc2);
            }
            float ce = (e2_[0] + e2_[1]) + (e2_[2] + e2_[3]);
            float C0 = fmaf(e2_[3], cvp[3][l][0], fmaf(e2_[2], cvp[2][l][0], fmaf(e2_[1], cvp[1][l][0], e2_[0] * cvp[0][l][0])));
            float C1 = fmaf(e2_[3], cvp[3][l][1], fmaf(e2_[2], cvp[2][l][1], fmaf(e2_[1], cvp[1][l][1], e2_[0] * cvp[0][l][1])));
            float C2 = fmaf(e2_[3], cvp[3][l][2], fmaf(e2_[2], cvp[2][l][2], fmaf(e2_[1], cvp[1][l][2], e2_[0] * cvp[0][l][2])));
            hsum16_4(ce, C0, C1, C2);
            // y1 materialization (off the CA-reduce path)
            float y1_0 = fmaf(z0 - mu, rstd1 * N1w[l][0], N1b[l][0]);
            float y1_1 = fmaf(z1 - mu, rstd1 * N1w[l][1], N1b[l][1]);
            float y1_2 = fmaf(z2v - mu, rstd1 * N1w[l][2], N1b[l][2]);
            float yc0 = y1_0 + Bco[l][0], yc1 = y1_1 + Bco[l][1], yc2 = y1_2 + Bco[l][2];
            // scale-invariant again: g = yc*ce + C
            float g0 = fmaf(yc0, ce, C0), g1 = fmaf(yc1, ce, C1), g2 = fmaf(yc2, ce, C2);
            float cee = ce * ce;

            // ---- LN2 + folded FF1 (rstd2 on chain; y2 off-chain)
            float t1m = (g0 + g1) + g2;
            float mu2 = t1m * (1.0f / 3.0f);
            float c20 = g0 - mu2, c21 = g1 - mu2, c22 = g2 - mu2;
            float t2m = fmaf(g0, g0, fmaf(g1, g1, g2 * g2));
            float vpe2 = fmaf(t2m, (1.0f / 3.0f), fmaf(-mu2, mu2, 1e-5f * cee));
            float rstd2 = __builtin_amdgcn_rsqf(vpe2);
            #pragma unroll
            for (int k = 0; k < 37; ++k) PIN(wv[k]);
            float d0 = fmaf(wv[0], c20, fmaf(wv[1],  c21, wv[2]  * c22));
            float d1 = fmaf(wv[3], c20, fmaf(wv[4],  c21, wv[5]  * c22));
            float d2 = fmaf(wv[6], c20, fmaf(wv[7],  c21, wv[8]  * c22));
            float d3 = fmaf(wv[9], c20, fmaf(wv[10], c21, wv[11] * c22));
            float h0 = fmaxf(fmaf(rstd2, d0, wv[12]), 0.f);
            float h1 = fmaxf(fmaf(rstd2, d1, wv[13]), 0.f);
            float h2 = fmaxf(fmaf(rstd2, d2, wv[14]), 0.f);
            float h3 = fmaxf(fmaf(rstd2, d3, wv[15]), 0.f);
            // y2 materialization (parallel)
            float y2_0 = fmaf(c20, rstd2 * N2w[l][0], N2b[l][0]);
            float y2_1 = fmaf(c21, rstd2 * N2w[l][1], N2b[l][1]);
            float y2_2 = fmaf(c22, rstd2 * N2w[l][2], N2b[l][2]);
            float yf0 = y2_0 + wv[28], yf1 = y2_1 + wv[29], yf2 = y2_2 + wv[30];
            float f0 = fmaf(wv[16], h0, fmaf(wv[17], h1, fmaf(wv[18], h2, fmaf(wv[19], h3, yf0))));
            float f1 = fmaf(wv[20], h0, fmaf(wv[21], h1, fmaf(wv[22], h2, fmaf(wv[23], h3, yf1))));
            float f2 = fmaf(wv[24], h0, fmaf(wv[25], h1, fmaf(wv[26], h2, fmaf(wv[27], h3, yf2))));
            ln3e(f0, f1, f2,
                 wv[31], wv[32], wv[33], wv[34], wv[35], wv[36],
                 y0, y1, y2);
        }
        if (j16 == 0) {
            out[(bb * S_ + i + 1) * 5 + 0] = y0;
            out[(bb * S_ + i + 1) * 5 + 1] = y1;
            out[(bb * S_ + i + 1) * 5 + 2] = y2;
        }
    }
}

// ---------------------------------------------------------------------------
extern "C" void kernel_launch(void* const* d_in, const int* in_sizes, int n_in,
                              void* d_out, int out_size, void* d_ws, size_t ws_size,
                              hipStream_t stream) {
    const float* src  = (const float*)d_in[0];
    const float* wemb = (const float*)d_in[1];
    const float* semb = (const float*)d_in[2];

    float* mem = (float*)d_ws;           // [B,S,3] scratch
    float* out = (float*)d_out;          // [B,S,5]

    enc_kernel<<<B_, 512, 0, stream>>>(
        src, wemb, semb,
        (const float*)d_in[3],  (const float*)d_in[4],
        (const float*)d_in[5],  (const float*)d_in[6],
        (const float*)d_in[7],  (const float*)d_in[8],
        (const float*)d_in[9],  (const float*)d_in[10],
        (const float*)d_in[11], (const float*)d_in[12],
        (const float*)d_in[13], (const float*)d_in[14],
        (const float*)d_in[15], (const float*)d_in[16],
        (const float*)d_in[17], (const float*)d_in[18],
        mem, out);

    dec_kernel<<<B_ / 4, 64, 0, stream>>>(
        mem,
        (const float*)d_in[19], (const float*)d_in[20],
        (const float*)d_in[21], (const float*)d_in[22],
        (const float*)d_in[23], (const float*)d_in[24],
        (const float*)d_in[25], (const float*)d_in[26],
        (const float*)d_in[27], (const float*)d_in[28],
        (const float*)d_in[29], (const float*)d_in[30],
        (const float*)d_in[31], (const float*)d_in[32],
        (const float*)d_in[33], (const float*)d_in[34],
        (const float*)d_in[35], (const float*)d_in[36],
        out);
}

// Round 7
// 365.071 us; speedup vs baseline: 1.1597x; 1.1597x over previous
//
#include <hip/hip_runtime.h>
#include <math.h>

#define B_ 64
#define S_ 64
#define U_ 16
#define EMB_ 10
#define D_ 34
#define DD_ 3
#define FF_ 4
#define NL_ 4

typedef float v2f __attribute__((ext_vector_type(2)));

// ---------------------------------------------------------------------------
// Kernel A: encoder — EXACT R13 (measured best: total 336.2 µs, enc ~63.7).
// FROZEN.
// ---------------------------------------------------------------------------
__global__ __launch_bounds__(512) void enc_kernel(
    const float* __restrict__ src, const float* __restrict__ wemb,
    const float* __restrict__ semb,
    const float* __restrict__ qkv_w, const float* __restrict__ qkv_b,
    const float* __restrict__ out_w, const float* __restrict__ out_b,
    const float* __restrict__ ln1_w, const float* __restrict__ ln1_b,
    const float* __restrict__ lin1_w, const float* __restrict__ lin1_b,
    const float* __restrict__ lin2_w, const float* __restrict__ lin2_b,
    const float* __restrict__ ln2_w, const float* __restrict__ ln2_b,
    const float* __restrict__ norm_w, const float* __restrict__ norm_b,
    const float* __restrict__ eo_w, const float* __restrict__ eo_b,
    float* __restrict__ mem, float* __restrict__ out)
{
    const int b = blockIdx.x;
    const int tid = threadIdx.x;
    const int wv_ = tid >> 6;
    const int lane = tid & 63;

    __shared__ float xs[S_][D_ + 1];
    __shared__ float tmp[S_][D_ + 1];
    __shared__ float att[S_][D_ + 1];
    __shared__ __align__(16) float qsh[2][S_][21];
    __shared__ __align__(16) float ksh[2][S_][20];
    __shared__ __align__(16) float vsh[2][S_][20];
    __shared__ float ffh[S_][5];
    __shared__ float pacc[4][128][19];

    const float rs17 = 0.24253562503633297f;
    const float negln = -logf(10000.0f) / (float)D_;

    // ---- embed + positional encoding
    #pragma unroll
    for (int rr = 0; rr < 5; ++rr) {
        int idx = tid + rr * 512;
        if (idx < S_ * D_) {
            int pos = idx / D_, d = idx % D_;
            float v;
            if (d < U_ - 2) {
                v = src[(b * S_ + pos) * U_ + d];
            } else if (d < U_ - 2 + EMB_) {
                int wi = (int)src[(b * S_ + pos) * U_ + (U_ - 2)];
                v = wemb[wi * EMB_ + (d - (U_ - 2))];
            } else {
                int si = (int)src[(b * S_ + pos) * U_ + (U_ - 1)];
                v = semb[si * EMB_ + (d - (U_ - 2 + EMB_))];
            }
            int k = d >> 1;
            float div = __expf((float)(2 * k) * negln);
            float ang = (float)b * div;
            v += (d & 1) ? __cosf(ang) : __sinf(ang);
            xs[pos][d] = v;
        }
    }
    __syncthreads();

    for (int l = 0; l < NL_; ++l) {
        const float* Wq = qkv_w + l * 3 * D_ * D_;
        const float* Bq = qkv_b + l * 3 * D_;

        // ---- qkv: lane = pos; wave owns rows r = wv_ + 8k; pk_fma dot
        {
            v2f xr2[17];
            #pragma unroll
            for (int d2 = 0; d2 < 17; ++d2) {
                v2f t; t.x = xs[lane][2 * d2]; t.y = xs[lane][2 * d2 + 1];
                xr2[d2] = t;
            }
            #pragma unroll
            for (int rb = 0; rb < 13; ++rb) {
                int r = wv_ + (rb << 3);
                if (r < 3 * D_) {
                    int ru = __builtin_amdgcn_readfirstlane(r);
                    const v2f* w2 = (const v2f*)(Wq + ru * D_);
                    v2f a2; a2.x = Bq[ru]; a2.y = 0.f;
                    #pragma unroll
                    for (int d2 = 0; d2 < 17; ++d2)
                        a2 = __builtin_elementwise_fma(xr2[d2], w2[d2], a2);
                    float acc = a2.x + a2.y;
                    if (ru < D_)          { int h = (ru >= 17), dd = ru - h * 17; qsh[h][lane][dd] = acc; }
                    else if (ru < 2 * D_) { int rr2 = ru - D_;     int h = (rr2 >= 17), dd = rr2 - h * 17; ksh[h][lane][dd] = acc; }
                    else                  { int rr2 = ru - 2 * D_; int h = (rr2 >= 17), dd = rr2 - h * 17; vsh[h][lane][dd] = acc; }
                }
            }
        }
        __syncthreads();

        // ---- attention, 4-way key-parallel
        {
            int c = tid >> 7, hq = tid & 127;
            int h = hq >> 6, qi = hq & 63;
            float qv[17], acc[17];
            #pragma unroll
            for (int d = 0; d < 17; ++d) { qv[d] = qsh[h][qi][d]; acc[d] = 0.f; }
            float ssum = 0.f;
            int j0 = c * 16;
            #pragma unroll 4
            for (int jj = 0; jj < 16; ++jj) {
                int j = j0 + jj;
                const float4* kr = (const float4*)ksh[h][j];
                const float4* vr = (const float4*)vsh[h][j];
                float4 k0 = kr[0], k1 = kr[1], k2 = kr[2], k3 = kr[3];
                float  k16 = ksh[h][j][16];
                float4 v0 = vr[0], v1 = vr[1], v2 = vr[2], v3 = vr[3];
                float  v16 = vsh[h][j][16];
                float sE = qv[0]*k0.x + qv[2]*k0.z + qv[4]*k1.x + qv[6]*k1.z +
                           qv[8]*k2.x + qv[10]*k2.z + qv[12]*k3.x + qv[14]*k3.z;
                float sO = qv[1]*k0.y + qv[3]*k0.w + qv[5]*k1.y + qv[7]*k1.w +
                           qv[9]*k2.y + qv[11]*k2.w + qv[13]*k3.y + qv[15]*k3.w;
                float sc = sE + sO + qv[16]*k16;
                float e = __expf(sc * rs17);
                ssum += e;
                acc[0] += e*v0.x;  acc[1] += e*v0.y;  acc[2] += e*v0.z;  acc[3] += e*v0.w;
                acc[4] += e*v1.x;  acc[5] += e*v1.y;  acc[6] += e*v1.z;  acc[7] += e*v1.w;
                acc[8] += e*v2.x;  acc[9] += e*v2.y;  acc[10] += e*v2.z; acc[11] += e*v2.w;
                acc[12] += e*v3.x; acc[13] += e*v3.y; acc[14] += e*v3.z; acc[15] += e*v3.w;
                acc[16] += e*v16;
            }
            #pragma unroll
            for (int d = 0; d < 17; ++d) pacc[c][hq][d] = acc[d];
            pacc[c][hq][17] = ssum;
        }
        __syncthreads();

        if (tid < 128) {
            int h = tid >> 6, qi = tid & 63;
            int off = h * 17;
            float ssum = pacc[0][tid][17] + pacc[1][tid][17] +
                         pacc[2][tid][17] + pacc[3][tid][17];
            float inv = 1.f / ssum;
            #pragma unroll
            for (int d = 0; d < 17; ++d)
                att[qi][off + d] = (pacc[0][tid][d] + pacc[1][tid][d] +
                                    pacc[2][tid][d] + pacc[3][tid][d]) * inv;
        }
        __syncthreads();

        // ---- out proj + residual (pk_fma)
        {
            v2f ar2[17];
            #pragma unroll
            for (int d2 = 0; d2 < 17; ++d2) {
                v2f t; t.x = att[lane][2 * d2]; t.y = att[lane][2 * d2 + 1];
                ar2[d2] = t;
            }
            const float* Wo = out_w + l * D_ * D_;
            const float* Bo = out_b + l * D_;
            #pragma unroll
            for (int rb = 0; rb < 5; ++rb) {
                int d = wv_ + (rb << 3);
                if (d < D_) {
                    int du = __builtin_amdgcn_readfirstlane(d);
                    const v2f* w2 = (const v2f*)(Wo + du * D_);
                    v2f a2; a2.x = Bo[du]; a2.y = 0.f;
                    #pragma unroll
                    for (int d2 = 0; d2 < 17; ++d2)
                        a2 = __builtin_elementwise_fma(ar2[d2], w2[d2], a2);
                    tmp[lane][du] = xs[lane][du] + a2.x + a2.y;
                }
            }
        }
        __syncthreads();

        // ---- LN1: 8 threads/row (all 512 active), shfl_xor(8) reduction
        {
            int row = tid >> 3, sub = tid & 7;
            float s = 0.f, sq = 0.f;
            #pragma unroll
            for (int d = sub; d < D_; d += 8) { float t = tmp[row][d]; s += t; sq = fmaf(t, t, sq); }
            #pragma unroll
            for (int m = 1; m < 8; m <<= 1) { s += __shfl_xor(s, m, 8); sq += __shfl_xor(sq, m, 8); }
            float mu = s * (1.0f / D_);
            float var = fmaf(sq, 1.0f / D_, -mu * mu);
            float rstd = rsqrtf(var + 1e-5f);
            #pragma unroll
            for (int d = sub; d < D_; d += 8)
                xs[row][d] = (tmp[row][d] - mu) * rstd * ln1_w[l * D_ + d] + ln1_b[l * D_ + d];
        }
        __syncthreads();

        // ---- FF1 (34 -> 4, relu): waves 0..3 (pk_fma)
        if (wv_ < 4) {
            int fu = __builtin_amdgcn_readfirstlane(wv_);
            const v2f* w2 = (const v2f*)(lin1_w + l * FF_ * D_ + fu * D_);
            v2f a2; a2.x = lin1_b[l * FF_ + fu]; a2.y = 0.f;
            #pragma unroll
            for (int d2 = 0; d2 < 17; ++d2) {
                v2f t; t.x = xs[lane][2 * d2]; t.y = xs[lane][2 * d2 + 1];
                a2 = __builtin_elementwise_fma(t, w2[d2], a2);
            }
            ffh[lane][fu] = fmaxf(a2.x + a2.y, 0.f);
        }
        __syncthreads();

        // ---- FF2 (4 -> 34) + residual
        {
            float h0 = ffh[lane][0], h1 = ffh[lane][1],
                  h2 = ffh[lane][2], h3 = ffh[lane][3];
            const float* W2 = lin2_w + l * D_ * FF_;
            const float* B2 = lin2_b + l * D_;
            #pragma unroll
            for (int rb = 0; rb < 5; ++rb) {
                int d = wv_ + (rb << 3);
                if (d < D_) {
                    int du = __builtin_amdgcn_readfirstlane(d);
                    const float* wrow = W2 + du * FF_;
                    float acc = fmaf(h0, wrow[0], fmaf(h1, wrow[1],
                                fmaf(h2, wrow[2], fmaf(h3, wrow[3], B2[du]))));
                    tmp[lane][du] = xs[lane][du] + acc;
                }
            }
        }
        __syncthreads();

        // ---- LN2: 8 threads/row
        {
            int row = tid >> 3, sub = tid & 7;
            float s = 0.f, sq = 0.f;
            #pragma unroll
            for (int d = sub; d < D_; d += 8) { float t = tmp[row][d]; s += t; sq = fmaf(t, t, sq); }
            #pragma unroll
            for (int m = 1; m < 8; m <<= 1) { s += __shfl_xor(s, m, 8); sq += __shfl_xor(sq, m, 8); }
            float mu = s * (1.0f / D_);
            float var = fmaf(sq, 1.0f / D_, -mu * mu);
            float rstd = rsqrtf(var + 1e-5f);
            #pragma unroll
            for (int d = sub; d < D_; d += 8)
                xs[row][d] = (tmp[row][d] - mu) * rstd * ln2_w[l * D_ + d] + ln2_b[l * D_ + d];
        }
        __syncthreads();
    }

    // ---- final LayerNorm: 8 threads/row
    {
        int row = tid >> 3, sub = tid & 7;
        float s = 0.f, sq = 0.f;
        #pragma unroll
        for (int d = sub; d < D_; d += 8) { float t = xs[row][d]; s += t; sq = fmaf(t, t, sq); }
        #pragma unroll
        for (int m = 1; m < 8; m <<= 1) { s += __shfl_xor(s, m, 8); sq += __shfl_xor(sq, m, 8); }
        float mu = s * (1.0f / D_);
        float var = fmaf(sq, 1.0f / D_, -mu * mu);
        float rstd = rsqrtf(var + 1e-5f);
        #pragma unroll
        for (int d = sub; d < D_; d += 8)
            tmp[row][d] = (xs[row][d] - mu) * rstd * norm_w[d] + norm_b[d];
    }
    __syncthreads();

    // ---- memory = x @ eo_w.T + eo_b : waves 0..2 (pk_fma), reads tmp
    if (wv_ < 3) {
        int ru = __builtin_amdgcn_readfirstlane(wv_);
        const v2f* w2 = (const v2f*)(eo_w + ru * D_);
        v2f a2; a2.x = eo_b[ru]; a2.y = 0.f;
        #pragma unroll
        for (int d2 = 0; d2 < 17; ++d2) {
            v2f t; t.x = tmp[lane][2 * d2]; t.y = tmp[lane][2 * d2 + 1];
            a2 = __builtin_elementwise_fma(t, w2[d2], a2);
        }
        mem[(b * S_ + lane) * DD_ + ru] = a2.x + a2.y;
    }

    if (tid < S_) {
        out[(b * S_ + tid) * 5 + 3] = src[(b * S_ + tid) * U_ + (U_ - 2)];
        out[(b * S_ + tid) * 5 + 4] = src[(b * S_ + tid) * U_ + (U_ - 1)];
    }
}

// ---------------------------------------------------------------------------
// Kernel B: decoder — R21. R20 post-mortem: SIMT-batching halved per-batch
// cycles but spilled (~530 regs needed; WRITE_SIZE 80->216KB). R21 keeps the
// 4-batch/16-lane structure and evicts ~240 registers:
//   1. Cross-attn constants -> LDS (caxA/caxB float4[NL][4][64]); 8
//      ds_read_b128/layer issued at layer top, consumed mid-layer (latency
//      hidden under SA VALU; we're issue-bound, LDS pipe idle).
//   2. Wvp fold: vp = (Wso·Wv)·y + Wso·bv — removes Wso/Wv/Bv (-36 net regs,
//      -9 fma/layer).
//   3. N1/N2/Bco/Bso -> fst LDS stage (40->56 slots, -72 regs, +4 reads).
// Pinned persistent now: Wsq q/k 72 + Bsq 24 + Wvp 36 + Bvp 12 = 144; sk/sv 96.
// ---------------------------------------------------------------------------
#define PIN(x) asm volatile("" : "+v"(x))

template <int CTRL>
__device__ __forceinline__ void dpp4(float& a, float& b, float& c, float& d) {
    int ta = __builtin_amdgcn_update_dpp(0, __float_as_int(a), CTRL, 0xf, 0xf, true);
    int tb = __builtin_amdgcn_update_dpp(0, __float_as_int(b), CTRL, 0xf, 0xf, true);
    int tc = __builtin_amdgcn_update_dpp(0, __float_as_int(c), CTRL, 0xf, 0xf, true);
    int td = __builtin_amdgcn_update_dpp(0, __float_as_int(d), CTRL, 0xf, 0xf, true);
    a += __int_as_float(ta);
    b += __int_as_float(tb);
    c += __int_as_float(tc);
    d += __int_as_float(td);
}

// Sum within each 16-lane group; result lands in EVERY lane of the group.
__device__ __forceinline__ void hsum16_4(float& a, float& b, float& c, float& d) {
    dpp4<0xB1>(a, b, c, d);    // quad_perm [1,0,3,2] : xor 1
    dpp4<0x4E>(a, b, c, d);    // quad_perm [2,3,0,1] : xor 2
    dpp4<0x141>(a, b, c, d);   // row_half_mirror
    dpp4<0x140>(a, b, c, d);   // row_mirror
}

__device__ __forceinline__ void ln3e(float z0, float z1, float z2,
                                     float w0, float w1, float w2,
                                     float b0, float b1, float b2,
                                     float& o0, float& o1, float& o2) {
    float s1 = (z0 + z1) + z2;
    float s2 = fmaf(z0, z0, fmaf(z1, z1, z2 * z2));
    float mu = s1 * (1.0f / 3.0f);
    float vpe = fmaf(s2, (1.0f / 3.0f), fmaf(-mu, mu, 1e-5f));
    float rstd = __builtin_amdgcn_rsqf(vpe);
    o0 = fmaf(z0 - mu, rstd * w0, b0);
    o1 = fmaf(z1 - mu, rstd * w1, b1);
    o2 = fmaf(z2 - mu, rstd * w2, b2);
}

__global__ __launch_bounds__(64, 1) void dec_kernel(
    const float* __restrict__ mem,
    const float* __restrict__ sa_qkv_w, const float* __restrict__ sa_qkv_b,
    const float* __restrict__ sa_out_w, const float* __restrict__ sa_out_b,
    const float* __restrict__ gln1_w, const float* __restrict__ gln1_b,
    const float* __restrict__ ca_qkv_w, const float* __restrict__ ca_qkv_b,
    const float* __restrict__ ca_out_w, const float* __restrict__ ca_out_b,
    const float* __restrict__ gln2_w, const float* __restrict__ gln2_b,
    const float* __restrict__ l1_w, const float* __restrict__ l1_b,
    const float* __restrict__ l2_w, const float* __restrict__ l2_b,
    const float* __restrict__ gln3_w, const float* __restrict__ gln3_b,
    float* __restrict__ out)
{
    const int b0 = blockIdx.x * 4;
    const int lane = threadIdx.x;
    const int grp = lane >> 4, j16 = lane & 15;
    const int bb = b0 + grp;
    const float LOG2E = 1.4426950408889634f;
    const float rs3 = 0.5773502691896258f;
    const float QS = rs3 * LOG2E;   // score scale folded into weights, exp->exp2

    // ---- FF-tail + LN/bias weight stage (56 slots; LN2 fold on FF1 rows)
    __shared__ __align__(16) float fst[NL_][56];
    // ---- per-lane cross-attn constants (A: wcu0-2,swcu  B: cbb,cvp0-2)
    __shared__ __align__(16) float4 caxA[NL_][4][64];
    __shared__ __align__(16) float4 caxB[NL_][4][64];

    for (int t = lane; t < NL_ * 56; t += 64) {
        int l = t / 56, s = t % 56;
        float v = 0.f;
        if      (s < 12) v = l1_w[l * 12 + s] * gln2_w[l * 3 + (s % 3)];
        else if (s < 16) {
            int j = s - 12;
            v = l1_w[l * 12 + j * 3 + 0] * gln2_b[l * 3 + 0] +
                l1_w[l * 12 + j * 3 + 1] * gln2_b[l * 3 + 1] +
                l1_w[l * 12 + j * 3 + 2] * gln2_b[l * 3 + 2] + l1_b[l * 4 + j];
        }
        else if (s < 28) v = l2_w[l * 12 + (s - 16)];
        else if (s < 31) v = l2_b[l * 3 + (s - 28)];
        else if (s < 34) v = gln3_w[l * 3 + (s - 31)];
        else if (s < 37) v = gln3_b[l * 3 + (s - 34)];
        else if (s < 40) v = gln2_w[l * 3 + (s - 37)];   // N2w
        else if (s < 43) v = gln2_b[l * 3 + (s - 40)];   // N2b
        else if (s < 46) v = gln1_w[l * 3 + (s - 43)];   // N1w
        else if (s < 49) v = gln1_b[l * 3 + (s - 46)];   // N1b
        else if (s < 52) v = ca_out_b[l * 3 + (s - 49)]; // Bco
        else if (s < 55) v = sa_out_b[l * 3 + (s - 52)]; // Bso
        fst[l][s] = v;
    }

    // ---- persistent pinned weights: SA q/k rows + folded value path
    float Wsq[NL_][6][3], Bsq[NL_][6];
    float Wvp[NL_][3][3], Bvp[NL_][3];

    #pragma unroll
    for (int l = 0; l < NL_; ++l) {
        #pragma unroll
        for (int r = 0; r < 6; ++r) {
            float sc = (r < 3) ? QS : 1.0f;
            Bsq[l][r] = sa_qkv_b[l * 9 + r] * sc;
            #pragma unroll
            for (int c = 0; c < 3; ++c) Wsq[l][r][c] = sa_qkv_w[l * 27 + r * 3 + c] * sc;
        }
        // Wvp = Wso·Wv, Bvp = Wso·Bv
        #pragma unroll
        for (int r = 0; r < 3; ++r) {
            float w0 = sa_out_w[l * 9 + r * 3 + 0];
            float w1 = sa_out_w[l * 9 + r * 3 + 1];
            float w2 = sa_out_w[l * 9 + r * 3 + 2];
            Bvp[l][r] = w0 * sa_qkv_b[l * 9 + 6] + w1 * sa_qkv_b[l * 9 + 7] + w2 * sa_qkv_b[l * 9 + 8];
            #pragma unroll
            for (int c = 0; c < 3; ++c)
                Wvp[l][r][c] = w0 * sa_qkv_w[l * 27 + 6 * 3 + c] +
                               w1 * sa_qkv_w[l * 27 + 7 * 3 + c] +
                               w2 * sa_qkv_w[l * 27 + 8 * 3 + c];
        }
    }

    // ---- per-slot cross-attn K/V + query-side folds -> LDS
    #pragma unroll
    for (int s4 = 0; s4 < 4; ++s4) {
        float m0 = mem[(bb * S_ + s4 * 16 + j16) * DD_ + 0];
        float m1 = mem[(bb * S_ + s4 * 16 + j16) * DD_ + 1];
        float m2 = mem[(bb * S_ + s4 * 16 + j16) * DD_ + 2];
        #pragma unroll
        for (int l = 0; l < NL_; ++l) {
            float ck[3], cv[3], cuv[3];
            #pragma unroll
            for (int r = 0; r < 3; ++r) {
                ck[r] = ca_qkv_w[l * 27 + (3 + r) * 3 + 0] * m0 +
                        ca_qkv_w[l * 27 + (3 + r) * 3 + 1] * m1 +
                        ca_qkv_w[l * 27 + (3 + r) * 3 + 2] * m2 + ca_qkv_b[l * 9 + 3 + r];
                cv[r] = ca_qkv_w[l * 27 + (6 + r) * 3 + 0] * m0 +
                        ca_qkv_w[l * 27 + (6 + r) * 3 + 1] * m1 +
                        ca_qkv_w[l * 27 + (6 + r) * 3 + 2] * m2 + ca_qkv_b[l * 9 + 6 + r];
            }
            #pragma unroll
            for (int s = 0; s < 3; ++s)
                cuv[s] = QS * (ca_qkv_w[l * 27 + 0 + s] * ck[0] +
                               ca_qkv_w[l * 27 + 3 + s] * ck[1] +
                               ca_qkv_w[l * 27 + 6 + s] * ck[2]);
            float cbv = QS * (ca_qkv_b[l * 9 + 0] * ck[0] +
                              ca_qkv_b[l * 9 + 1] * ck[1] +
                              ca_qkv_b[l * 9 + 2] * ck[2]);
            float cvp0 = ca_out_w[l * 9 + 0] * cv[0] + ca_out_w[l * 9 + 1] * cv[1] + ca_out_w[l * 9 + 2] * cv[2];
            float cvp1 = ca_out_w[l * 9 + 3] * cv[0] + ca_out_w[l * 9 + 4] * cv[1] + ca_out_w[l * 9 + 5] * cv[2];
            float cvp2 = ca_out_w[l * 9 + 6] * cv[0] + ca_out_w[l * 9 + 7] * cv[1] + ca_out_w[l * 9 + 8] * cv[2];
            float wcu0 = cuv[0] * gln1_w[l * 3 + 0];
            float wcu1 = cuv[1] * gln1_w[l * 3 + 1];
            float wcu2 = cuv[2] * gln1_w[l * 3 + 2];
            float swcu = wcu0 + wcu1 + wcu2;
            float cbbv = cbv + cuv[0] * gln1_b[l * 3 + 0] + cuv[1] * gln1_b[l * 3 + 1] + cuv[2] * gln1_b[l * 3 + 2];
            caxA[l][s4][lane] = make_float4(wcu0, wcu1, wcu2, swcu);
            caxB[l][s4][lane] = make_float4(cbbv, cvp0, cvp1, cvp2);
        }
    }
    __syncthreads();

    // ---- pin the persistent set (144 floats)
    #pragma unroll
    for (int l = 0; l < NL_; ++l) {
        #pragma unroll
        for (int r = 0; r < 6; ++r) {
            PIN(Bsq[l][r]);
            #pragma unroll
            for (int c = 0; c < 3; ++c) PIN(Wsq[l][r][c]);
        }
        #pragma unroll
        for (int r = 0; r < 3; ++r) {
            PIN(Bvp[l][r]);
            #pragma unroll
            for (int c = 0; c < 3; ++c) PIN(Wvp[l][r][c]);
        }
    }

    // self-attn KV cache: slot s holds position s*16 + j16 of this group's batch
    float sk[4][NL_][3] = {{{0.f}}}, sv[4][NL_][3] = {{{0.f}}};

    if (j16 < 3) out[(bb * S_ + 0) * 5 + j16] = 0.f;

    float y0 = 0.f, y1 = 0.f, y2 = 0.f;

    for (int i = 0; i < S_ - 1; ++i) {
        float msa[4];
        #pragma unroll
        for (int s = 0; s < 4; ++s)
            msa[s] = (s * 16 + j16 <= i) ? 0.f : -1.0e30f;
        bool lm = (j16 == (i & 15));

        #pragma unroll
        for (int l = 0; l < NL_; ++l) {
            // ---- loads at layer top: fst (14 x b128) + cax (8 x b128)
            float wv[56];
            {
                const float4* fp = (const float4*)fst[l];
                #pragma unroll
                for (int k = 0; k < 14; ++k) {
                    float4 t4 = fp[k];
                    wv[4 * k + 0] = t4.x; wv[4 * k + 1] = t4.y;
                    wv[4 * k + 2] = t4.z; wv[4 * k + 3] = t4.w;
                }
            }
            float cwcu[4][3], cswcu[4], ccbb[4], ccvp[4][3];
            #pragma unroll
            for (int s = 0; s < 4; ++s) {
                float4 a4 = caxA[l][s][lane];
                float4 b4 = caxB[l][s][lane];
                cwcu[s][0] = a4.x; cwcu[s][1] = a4.y; cwcu[s][2] = a4.z; cswcu[s] = a4.w;
                ccbb[s] = b4.x; ccvp[s][0] = b4.y; ccvp[s][1] = b4.z; ccvp[s][2] = b4.w;
            }

            // ---- causal self-attention (q pre-scaled by QS; vp via Wvp fold)
            float q[3], kn[3], vp[3];
            #pragma unroll
            for (int r = 0; r < 3; ++r) {
                kn[r] = fmaf(Wsq[l][3 + r][0], y0, fmaf(Wsq[l][3 + r][1], y1, fmaf(Wsq[l][3 + r][2], y2, Bsq[l][3 + r])));
                q[r]  = fmaf(Wsq[l][r][0], y0, fmaf(Wsq[l][r][1], y1, fmaf(Wsq[l][r][2], y2, Bsq[l][r])));
                vp[r] = fmaf(Wvp[l][r][0], y0, fmaf(Wvp[l][r][1], y1, fmaf(Wvp[l][r][2], y2, Bvp[l][r])));
            }
            // KV write: lane-match exec mask + uniform slot branch (static idx)
            if (lm) {
                if (i < 16) {
                    #pragma unroll
                    for (int r = 0; r < 3; ++r) { sk[0][l][r] = kn[r]; sv[0][l][r] = vp[r]; }
                } else if (i < 32) {
                    #pragma unroll
                    for (int r = 0; r < 3; ++r) { sk[1][l][r] = kn[r]; sv[1][l][r] = vp[r]; }
                } else if (i < 48) {
                    #pragma unroll
                    for (int r = 0; r < 3; ++r) { sk[2][l][r] = kn[r]; sv[2][l][r] = vp[r]; }
                } else {
                    #pragma unroll
                    for (int r = 0; r < 3; ++r) { sk[3][l][r] = kn[r]; sv[3][l][r] = vp[r]; }
                }
            }
            float e_[4];
            #pragma unroll
            for (int s = 0; s < 4; ++s) {
                float sc = fmaf(q[0], sk[s][l][0], fmaf(q[1], sk[s][l][1], fmaf(q[2], sk[s][l][2], msa[s])));
                e_[s] = __builtin_amdgcn_exp2f(sc);
            }
            float se = (e_[0] + e_[1]) + (e_[2] + e_[3]);
            float S0 = fmaf(e_[3], sv[3][l][0], fmaf(e_[2], sv[2][l][0], fmaf(e_[1], sv[1][l][0], e_[0] * sv[0][l][0])));
            float S1 = fmaf(e_[3], sv[3][l][1], fmaf(e_[2], sv[2][l][1], fmaf(e_[1], sv[1][l][1], e_[0] * sv[0][l][1])));
            float S2 = fmaf(e_[3], sv[3][l][2], fmaf(e_[2], sv[2][l][2], fmaf(e_[1], sv[1][l][2], e_[0] * sv[0][l][2])));
            hsum16_4(se, S0, S1, S2);
            // Bso from LDS stage (materialize here)
            PIN(wv[52]); PIN(wv[53]); PIN(wv[54]);
            float yb0 = y0 + wv[52], yb1 = y1 + wv[53], yb2 = y2 + wv[54];
            float z0 = fmaf(yb0, se, S0), z1 = fmaf(yb1, se, S1), z2v = fmaf(yb2, se, S2);
            float ee = se * se;

            // ---- LN1 + folded CA scores per slot (rstd on chain; y1 off-chain)
            float s1m = (z0 + z1) + z2v;
            float mu = s1m * (1.0f / 3.0f);
            float s2m = fmaf(z0, z0, fmaf(z1, z1, z2v * z2v));
            float vpe = fmaf(s2m, (1.0f / 3.0f), fmaf(-mu, mu, 1e-5f * ee));
            float rstd1 = __builtin_amdgcn_rsqf(vpe);
            // materialize cross-attn constants (loads issued at layer top)
            #pragma unroll
            for (int s = 0; s < 4; ++s) {
                PIN(cwcu[s][0]); PIN(cwcu[s][1]); PIN(cwcu[s][2]); PIN(cswcu[s]);
                PIN(ccbb[s]); PIN(ccvp[s][0]); PIN(ccvp[s][1]); PIN(ccvp[s][2]);
            }
            float e2_[4];
            #pragma unroll
            for (int s = 0; s < 4; ++s) {
                float zw = fmaf(z0, cwcu[s][0], fmaf(z1, cwcu[s][1], z2v * cwcu[s][2]));
                float inner = fmaf(-mu, cswcu[s], zw);
                float sc2 = fmaf(rstd1, inner, ccbb[s]);
                e2_[s] = __builtin_amdgcn_exp2f(sc2);
            }
            float ce = (e2_[0] + e2_[1]) + (e2_[2] + e2_[3]);
            float C0 = fmaf(e2_[3], ccvp[3][0], fmaf(e2_[2], ccvp[2][0], fmaf(e2_[1], ccvp[1][0], e2_[0] * ccvp[0][0])));
            float C1 = fmaf(e2_[3], ccvp[3][1], fmaf(e2_[2], ccvp[2][1], fmaf(e2_[1], ccvp[1][1], e2_[0] * ccvp[0][1])));
            float C2 = fmaf(e2_[3], ccvp[3][2], fmaf(e2_[2], ccvp[2][2], fmaf(e2_[1], ccvp[1][2], e2_[0] * ccvp[0][2])));
            hsum16_4(ce, C0, C1, C2);
            // y1 materialization (off the CA-reduce path); N1w/N1b/Bco from LDS
            PIN(wv[43]); PIN(wv[44]); PIN(wv[45]);
            PIN(wv[46]); PIN(wv[47]); PIN(wv[48]);
            PIN(wv[49]); PIN(wv[50]); PIN(wv[51]);
            float y1_0 = fmaf(z0 - mu, rstd1 * wv[43], wv[46]);
            float y1_1 = fmaf(z1 - mu, rstd1 * wv[44], wv[47]);
            float y1_2 = fmaf(z2v - mu, rstd1 * wv[45], wv[48]);
            float yc0 = y1_0 + wv[49], yc1 = y1_1 + wv[50], yc2 = y1_2 + wv[51];
            // scale-invariant again: g = yc*ce + C
            float g0 = fmaf(yc0, ce, C0), g1 = fmaf(yc1, ce, C1), g2 = fmaf(yc2, ce, C2);
            float cee = ce * ce;

            // ---- LN2 + folded FF1 (rstd2 on chain; y2 off-chain)
            float t1m = (g0 + g1) + g2;
            float mu2 = t1m * (1.0f / 3.0f);
            float c20 = g0 - mu2, c21 = g1 - mu2, c22 = g2 - mu2;
            float t2m = fmaf(g0, g0, fmaf(g1, g1, g2 * g2));
            float vpe2 = fmaf(t2m, (1.0f / 3.0f), fmaf(-mu2, mu2, 1e-5f * cee));
            float rstd2 = __builtin_amdgcn_rsqf(vpe2);
            #pragma unroll
            for (int k = 0; k < 43; ++k) PIN(wv[k]);
            float d0 = fmaf(wv[0], c20, fmaf(wv[1],  c21, wv[2]  * c22));
            float d1 = fmaf(wv[3], c20, fmaf(wv[4],  c21, wv[5]  * c22));
            float d2 = fmaf(wv[6], c20, fmaf(wv[7],  c21, wv[8]  * c22));
            float d3 = fmaf(wv[9], c20, fmaf(wv[10], c21, wv[11] * c22));
            float h0 = fmaxf(fmaf(rstd2, d0, wv[12]), 0.f);
            float h1 = fmaxf(fmaf(rstd2, d1, wv[13]), 0.f);
            float h2 = fmaxf(fmaf(rstd2, d2, wv[14]), 0.f);
            float h3 = fmaxf(fmaf(rstd2, d3, wv[15]), 0.f);
            // y2 materialization (parallel); N2w=wv[37..39], N2b=wv[40..42]
            float y2_0 = fmaf(c20, rstd2 * wv[37], wv[40]);
            float y2_1 = fmaf(c21, rstd2 * wv[38], wv[41]);
            float y2_2 = fmaf(c22, rstd2 * wv[39], wv[42]);
            float yf0 = y2_0 + wv[28], yf1 = y2_1 + wv[29], yf2 = y2_2 + wv[30];
            float f0 = fmaf(wv[16], h0, fmaf(wv[17], h1, fmaf(wv[18], h2, fmaf(wv[19], h3, yf0))));
            float f1 = fmaf(wv[20], h0, fmaf(wv[21], h1, fmaf(wv[22], h2, fmaf(wv[23], h3, yf1))));
            float f2 = fmaf(wv[24], h0, fmaf(wv[25], h1, fmaf(wv[26], h2, fmaf(wv[27], h3, yf2))));
            ln3e(f0, f1, f2,
                 wv[31], wv[32], wv[33], wv[34], wv[35], wv[36],
                 y0, y1, y2);
        }
        if (j16 == 0) {
            out[(bb * S_ + i + 1) * 5 + 0] = y0;
            out[(bb * S_ + i + 1) * 5 + 1] = y1;
            out[(bb * S_ + i + 1) * 5 + 2] = y2;
        }
    }
}

// ---------------------------------------------------------------------------
extern "C" void kernel_launch(void* const* d_in, const int* in_sizes, int n_in,
                              void* d_out, int out_size, void* d_ws, size_t ws_size,
                              hipStream_t stream) {
    const float* src  = (const float*)d_in[0];
    const float* wemb = (const float*)d_in[1];
    const float* semb = (const float*)d_in[2];

    float* mem = (float*)d_ws;           // [B,S,3] scratch
    float* out = (float*)d_out;          // [B,S,5]

    enc_kernel<<<B_, 512, 0, stream>>>(
        src, wemb, semb,
        (const float*)d_in[3],  (const float*)d_in[4],
        (const float*)d_in[5],  (const float*)d_in[6],
        (const float*)d_in[7],  (const float*)d_in[8],
        (const float*)d_in[9],  (const float*)d_in[10],
        (const float*)d_in[11], (const float*)d_in[12],
        (const float*)d_in[13], (const float*)d_in[14],
        (const float*)d_in[15], (const float*)d_in[16],
        (const float*)d_in[17], (const float*)d_in[18],
        mem, out);

    dec_kernel<<<B_ / 4, 64, 0, stream>>>(
        mem,
        (const float*)d_in[19], (const float*)d_in[20],
        (const float*)d_in[21], (const float*)d_in[22],
        (const float*)d_in[23], (const float*)d_in[24],
        (const float*)d_in[25], (const float*)d_in[26],
        (const float*)d_in[27], (const float*)d_in[28],
        (const float*)d_in[29], (const float*)d_in[30],
        (const float*)d_in[31], (const float*)d_in[32],
        (const float*)d_in[33], (const float*)d_in[34],
        (const float*)d_in[35], (const float*)d_in[36],
        out);
}

// Round 9
// 305.043 us; speedup vs baseline: 1.3879x; 1.1968x over previous
//
#include <hip/hip_runtime.h>
#include <math.h>

#define B_ 64
#define S_ 64
#define U_ 16
#define EMB_ 10
#define D_ 34
#define DD_ 3
#define FF_ 4
#define NL_ 4

typedef float v2f __attribute__((ext_vector_type(2)));

// ---------------------------------------------------------------------------
// Kernel A: encoder — EXACT R13 (measured best: total 336.2 µs, enc ~63.7).
// FROZEN.
// ---------------------------------------------------------------------------
__global__ __launch_bounds__(512) void enc_kernel(
    const float* __restrict__ src, const float* __restrict__ wemb,
    const float* __restrict__ semb,
    const float* __restrict__ qkv_w, const float* __restrict__ qkv_b,
    const float* __restrict__ out_w, const float* __restrict__ out_b,
    const float* __restrict__ ln1_w, const float* __restrict__ ln1_b,
    const float* __restrict__ lin1_w, const float* __restrict__ lin1_b,
    const float* __restrict__ lin2_w, const float* __restrict__ lin2_b,
    const float* __restrict__ ln2_w, const float* __restrict__ ln2_b,
    const float* __restrict__ norm_w, const float* __restrict__ norm_b,
    const float* __restrict__ eo_w, const float* __restrict__ eo_b,
    float* __restrict__ mem, float* __restrict__ out)
{
    const int b = blockIdx.x;
    const int tid = threadIdx.x;
    const int wv_ = tid >> 6;
    const int lane = tid & 63;

    __shared__ float xs[S_][D_ + 1];
    __shared__ float tmp[S_][D_ + 1];
    __shared__ float att[S_][D_ + 1];
    __shared__ __align__(16) float qsh[2][S_][21];
    __shared__ __align__(16) float ksh[2][S_][20];
    __shared__ __align__(16) float vsh[2][S_][20];
    __shared__ float ffh[S_][5];
    __shared__ float pacc[4][128][19];

    const float rs17 = 0.24253562503633297f;
    const float negln = -logf(10000.0f) / (float)D_;

    // ---- embed + positional encoding
    #pragma unroll
    for (int rr = 0; rr < 5; ++rr) {
        int idx = tid + rr * 512;
        if (idx < S_ * D_) {
            int pos = idx / D_, d = idx % D_;
            float v;
            if (d < U_ - 2) {
                v = src[(b * S_ + pos) * U_ + d];
            } else if (d < U_ - 2 + EMB_) {
                int wi = (int)src[(b * S_ + pos) * U_ + (U_ - 2)];
                v = wemb[wi * EMB_ + (d - (U_ - 2))];
            } else {
                int si = (int)src[(b * S_ + pos) * U_ + (U_ - 1)];
                v = semb[si * EMB_ + (d - (U_ - 2 + EMB_))];
            }
            int k = d >> 1;
            float div = __expf((float)(2 * k) * negln);
            float ang = (float)b * div;
            v += (d & 1) ? __cosf(ang) : __sinf(ang);
            xs[pos][d] = v;
        }
    }
    __syncthreads();

    for (int l = 0; l < NL_; ++l) {
        const float* Wq = qkv_w + l * 3 * D_ * D_;
        const float* Bq = qkv_b + l * 3 * D_;

        // ---- qkv: lane = pos; wave owns rows r = wv_ + 8k; pk_fma dot
        {
            v2f xr2[17];
            #pragma unroll
            for (int d2 = 0; d2 < 17; ++d2) {
                v2f t; t.x = xs[lane][2 * d2]; t.y = xs[lane][2 * d2 + 1];
                xr2[d2] = t;
            }
            #pragma unroll
            for (int rb = 0; rb < 13; ++rb) {
                int r = wv_ + (rb << 3);
                if (r < 3 * D_) {
                    int ru = __builtin_amdgcn_readfirstlane(r);
                    const v2f* w2 = (const v2f*)(Wq + ru * D_);
                    v2f a2; a2.x = Bq[ru]; a2.y = 0.f;
                    #pragma unroll
                    for (int d2 = 0; d2 < 17; ++d2)
                        a2 = __builtin_elementwise_fma(xr2[d2], w2[d2], a2);
                    float acc = a2.x + a2.y;
                    if (ru < D_)          { int h = (ru >= 17), dd = ru - h * 17; qsh[h][lane][dd] = acc; }
                    else if (ru < 2 * D_) { int rr2 = ru - D_;     int h = (rr2 >= 17), dd = rr2 - h * 17; ksh[h][lane][dd] = acc; }
                    else                  { int rr2 = ru - 2 * D_; int h = (rr2 >= 17), dd = rr2 - h * 17; vsh[h][lane][dd] = acc; }
                }
            }
        }
        __syncthreads();

        // ---- attention, 4-way key-parallel
        {
            int c = tid >> 7, hq = tid & 127;
            int h = hq >> 6, qi = hq & 63;
            float qv[17], acc[17];
            #pragma unroll
            for (int d = 0; d < 17; ++d) { qv[d] = qsh[h][qi][d]; acc[d] = 0.f; }
            float ssum = 0.f;
            int j0 = c * 16;
            #pragma unroll 4
            for (int jj = 0; jj < 16; ++jj) {
                int j = j0 + jj;
                const float4* kr = (const float4*)ksh[h][j];
                const float4* vr = (const float4*)vsh[h][j];
                float4 k0 = kr[0], k1 = kr[1], k2 = kr[2], k3 = kr[3];
                float  k16 = ksh[h][j][16];
                float4 v0 = vr[0], v1 = vr[1], v2 = vr[2], v3 = vr[3];
                float  v16 = vsh[h][j][16];
                float sE = qv[0]*k0.x + qv[2]*k0.z + qv[4]*k1.x + qv[6]*k1.z +
                           qv[8]*k2.x + qv[10]*k2.z + qv[12]*k3.x + qv[14]*k3.z;
                float sO = qv[1]*k0.y + qv[3]*k0.w + qv[5]*k1.y + qv[7]*k1.w +
                           qv[9]*k2.y + qv[11]*k2.w + qv[13]*k3.y + qv[15]*k3.w;
                float sc = sE + sO + qv[16]*k16;
                float e = __expf(sc * rs17);
                ssum += e;
                acc[0] += e*v0.x;  acc[1] += e*v0.y;  acc[2] += e*v0.z;  acc[3] += e*v0.w;
                acc[4] += e*v1.x;  acc[5] += e*v1.y;  acc[6] += e*v1.z;  acc[7] += e*v1.w;
                acc[8] += e*v2.x;  acc[9] += e*v2.y;  acc[10] += e*v2.z; acc[11] += e*v2.w;
                acc[12] += e*v3.x; acc[13] += e*v3.y; acc[14] += e*v3.z; acc[15] += e*v3.w;
                acc[16] += e*v16;
            }
            #pragma unroll
            for (int d = 0; d < 17; ++d) pacc[c][hq][d] = acc[d];
            pacc[c][hq][17] = ssum;
        }
        __syncthreads();

        if (tid < 128) {
            int h = tid >> 6, qi = tid & 63;
            int off = h * 17;
            float ssum = pacc[0][tid][17] + pacc[1][tid][17] +
                         pacc[2][tid][17] + pacc[3][tid][17];
            float inv = 1.f / ssum;
            #pragma unroll
            for (int d = 0; d < 17; ++d)
                att[qi][off + d] = (pacc[0][tid][d] + pacc[1][tid][d] +
                                    pacc[2][tid][d] + pacc[3][tid][d]) * inv;
        }
        __syncthreads();

        // ---- out proj + residual (pk_fma)
        {
            v2f ar2[17];
            #pragma unroll
            for (int d2 = 0; d2 < 17; ++d2) {
                v2f t; t.x = att[lane][2 * d2]; t.y = att[lane][2 * d2 + 1];
                ar2[d2] = t;
            }
            const float* Wo = out_w + l * D_ * D_;
            const float* Bo = out_b + l * D_;
            #pragma unroll
            for (int rb = 0; rb < 5; ++rb) {
                int d = wv_ + (rb << 3);
                if (d < D_) {
                    int du = __builtin_amdgcn_readfirstlane(d);
                    const v2f* w2 = (const v2f*)(Wo + du * D_);
                    v2f a2; a2.x = Bo[du]; a2.y = 0.f;
                    #pragma unroll
                    for (int d2 = 0; d2 < 17; ++d2)
                        a2 = __builtin_elementwise_fma(ar2[d2], w2[d2], a2);
                    tmp[lane][du] = xs[lane][du] + a2.x + a2.y;
                }
            }
        }
        __syncthreads();

        // ---- LN1: 8 threads/row (all 512 active), shfl_xor(8) reduction
        {
            int row = tid >> 3, sub = tid & 7;
            float s = 0.f, sq = 0.f;
            #pragma unroll
            for (int d = sub; d < D_; d += 8) { float t = tmp[row][d]; s += t; sq = fmaf(t, t, sq); }
            #pragma unroll
            for (int m = 1; m < 8; m <<= 1) { s += __shfl_xor(s, m, 8); sq += __shfl_xor(sq, m, 8); }
            float mu = s * (1.0f / D_);
            float var = fmaf(sq, 1.0f / D_, -mu * mu);
            float rstd = rsqrtf(var + 1e-5f);
            #pragma unroll
            for (int d = sub; d < D_; d += 8)
                xs[row][d] = (tmp[row][d] - mu) * rstd * ln1_w[l * D_ + d] + ln1_b[l * D_ + d];
        }
        __syncthreads();

        // ---- FF1 (34 -> 4, relu): waves 0..3 (pk_fma)
        if (wv_ < 4) {
            int fu = __builtin_amdgcn_readfirstlane(wv_);
            const v2f* w2 = (const v2f*)(lin1_w + l * FF_ * D_ + fu * D_);
            v2f a2; a2.x = lin1_b[l * FF_ + fu]; a2.y = 0.f;
            #pragma unroll
            for (int d2 = 0; d2 < 17; ++d2) {
                v2f t; t.x = xs[lane][2 * d2]; t.y = xs[lane][2 * d2 + 1];
                a2 = __builtin_elementwise_fma(t, w2[d2], a2);
            }
            ffh[lane][fu] = fmaxf(a2.x + a2.y, 0.f);
        }
        __syncthreads();

        // ---- FF2 (4 -> 34) + residual
        {
            float h0 = ffh[lane][0], h1 = ffh[lane][1],
                  h2 = ffh[lane][2], h3 = ffh[lane][3];
            const float* W2 = lin2_w + l * D_ * FF_;
            const float* B2 = lin2_b + l * D_;
            #pragma unroll
            for (int rb = 0; rb < 5; ++rb) {
                int d = wv_ + (rb << 3);
                if (d < D_) {
                    int du = __builtin_amdgcn_readfirstlane(d);
                    const float* wrow = W2 + du * FF_;
                    float acc = fmaf(h0, wrow[0], fmaf(h1, wrow[1],
                                fmaf(h2, wrow[2], fmaf(h3, wrow[3], B2[du]))));
                    tmp[lane][du] = xs[lane][du] + acc;
                }
            }
        }
        __syncthreads();

        // ---- LN2: 8 threads/row
        {
            int row = tid >> 3, sub = tid & 7;
            float s = 0.f, sq = 0.f;
            #pragma unroll
            for (int d = sub; d < D_; d += 8) { float t = tmp[row][d]; s += t; sq = fmaf(t, t, sq); }
            #pragma unroll
            for (int m = 1; m < 8; m <<= 1) { s += __shfl_xor(s, m, 8); sq += __shfl_xor(sq, m, 8); }
            float mu = s * (1.0f / D_);
            float var = fmaf(sq, 1.0f / D_, -mu * mu);
            float rstd = rsqrtf(var + 1e-5f);
            #pragma unroll
            for (int d = sub; d < D_; d += 8)
                xs[row][d] = (tmp[row][d] - mu) * rstd * ln2_w[l * D_ + d] + ln2_b[l * D_ + d];
        }
        __syncthreads();
    }

    // ---- final LayerNorm: 8 threads/row
    {
        int row = tid >> 3, sub = tid & 7;
        float s = 0.f, sq = 0.f;
        #pragma unroll
        for (int d = sub; d < D_; d += 8) { float t = xs[row][d]; s += t; sq = fmaf(t, t, sq); }
        #pragma unroll
        for (int m = 1; m < 8; m <<= 1) { s += __shfl_xor(s, m, 8); sq += __shfl_xor(sq, m, 8); }
        float mu = s * (1.0f / D_);
        float var = fmaf(sq, 1.0f / D_, -mu * mu);
        float rstd = rsqrtf(var + 1e-5f);
        #pragma unroll
        for (int d = sub; d < D_; d += 8)
            tmp[row][d] = (xs[row][d] - mu) * rstd * norm_w[d] + norm_b[d];
    }
    __syncthreads();

    // ---- memory = x @ eo_w.T + eo_b : waves 0..2 (pk_fma), reads tmp
    if (wv_ < 3) {
        int ru = __builtin_amdgcn_readfirstlane(wv_);
        const v2f* w2 = (const v2f*)(eo_w + ru * D_);
        v2f a2; a2.x = eo_b[ru]; a2.y = 0.f;
        #pragma unroll
        for (int d2 = 0; d2 < 17; ++d2) {
            v2f t; t.x = tmp[lane][2 * d2]; t.y = tmp[lane][2 * d2 + 1];
            a2 = __builtin_elementwise_fma(t, w2[d2], a2);
        }
        mem[(b * S_ + lane) * DD_ + ru] = a2.x + a2.y;
    }

    if (tid < S_) {
        out[(b * S_ + tid) * 5 + 3] = src[(b * S_ + tid) * U_ + (U_ - 2)];
        out[(b * S_ + tid) * 5 + 4] = src[(b * S_ + tid) * U_ + (U_ - 1)];
    }
}

// ---------------------------------------------------------------------------
// Kernel B: decoder — R23. R22 (pk_fma packing + vector PIN) core-dumped;
// suspects: asm "+v" on v2f operands / vector elementwise_max. R23 = EXACT
// R19 structure (proven passing, dec 135.0 µs) + scalar-safe folds only:
//   1. Wvp fold (validated in R21): vp = (Wso·Wv)·y + Wso·bv directly —
//      deletes the vn intermediate (-9 fma/layer), retires Wso.
//   2. Bias folds: N1bF = gln1_b + Bco -> yc in one fma; N2bF = gln2_b +
//      l2_b -> yf in one fma (-6 adds/layer). cbb still uses true gln1_b.
// All scalar fmaf / scalar PIN — identical machinery to R19.
// ---------------------------------------------------------------------------
#define PIN(x) asm volatile("" : "+v"(x))

template <int N> struct IC { static constexpr int value = N; };

template <int CTRL>
__device__ __forceinline__ void dpp4(float& a, float& b, float& c, float& d) {
    int ta = __builtin_amdgcn_update_dpp(0, __float_as_int(a), CTRL, 0xf, 0xf, true);
    int tb = __builtin_amdgcn_update_dpp(0, __float_as_int(b), CTRL, 0xf, 0xf, true);
    int tc = __builtin_amdgcn_update_dpp(0, __float_as_int(c), CTRL, 0xf, 0xf, true);
    int td = __builtin_amdgcn_update_dpp(0, __float_as_int(d), CTRL, 0xf, 0xf, true);
    a += __int_as_float(ta);
    b += __int_as_float(tb);
    c += __int_as_float(tc);
    d += __int_as_float(td);
}

__device__ __forceinline__ void red16_4(float& a, float& b, float& c, float& d) {
    dpp4<0x111>(a, b, c, d);
    dpp4<0x112>(a, b, c, d);
    dpp4<0x114>(a, b, c, d);
    dpp4<0x118>(a, b, c, d);   // lane 15 of each row = row sum
}

template <int L>
__device__ __forceinline__ float rlane(float v) {
    return __int_as_float(__builtin_amdgcn_readlane(__float_as_int(v), L));
}

__device__ __forceinline__ void ln3e(float z0, float z1, float z2,
                                     float w0, float w1, float w2,
                                     float b0, float b1, float b2,
                                     float& o0, float& o1, float& o2) {
    float s1 = (z0 + z1) + z2;
    float s2 = fmaf(z0, z0, fmaf(z1, z1, z2 * z2));
    float mu = s1 * (1.0f / 3.0f);
    float vpe = fmaf(s2, (1.0f / 3.0f), fmaf(-mu, mu, 1e-5f));
    float rstd = __builtin_amdgcn_rsqf(vpe);
    o0 = fmaf(z0 - mu, rstd * w0, b0);
    o1 = fmaf(z1 - mu, rstd * w1, b1);
    o2 = fmaf(z2 - mu, rstd * w2, b2);
}

__global__ __launch_bounds__(64, 1) void dec_kernel(
    const float* __restrict__ mem,
    const float* __restrict__ sa_qkv_w, const float* __restrict__ sa_qkv_b,
    const float* __restrict__ sa_out_w, const float* __restrict__ sa_out_b,
    const float* __restrict__ gln1_w, const float* __restrict__ gln1_b,
    const float* __restrict__ ca_qkv_w, const float* __restrict__ ca_qkv_b,
    const float* __restrict__ ca_out_w, const float* __restrict__ ca_out_b,
    const float* __restrict__ gln2_w, const float* __restrict__ gln2_b,
    const float* __restrict__ l1_w, const float* __restrict__ l1_b,
    const float* __restrict__ l2_w, const float* __restrict__ l2_b,
    const float* __restrict__ gln3_w, const float* __restrict__ gln3_b,
    float* __restrict__ out)
{
    const int b = blockIdx.x;
    const int lane = threadIdx.x;
    const float LOG2E = 1.4426950408889634f;
    const float rs3 = 0.5773502691896258f;
    const float QS = rs3 * LOG2E;   // score scale folded into weights, exp->exp2

    // ---- FF-tail weight stage: W1N = W1 ∘ N2w, b1n = W1·N2b + b1 (LN2 fold)
    __shared__ __align__(16) float fst[NL_][40];
    for (int t = lane; t < NL_ * 40; t += 64) {
        int l = t / 40, s = t % 40;
        float v = 0.f;
        if      (s < 12) v = l1_w[l * 12 + s] * gln2_w[l * 3 + (s % 3)];
        else if (s < 16) {
            int j = s - 12;
            v = l1_w[l * 12 + j * 3 + 0] * gln2_b[l * 3 + 0] +
                l1_w[l * 12 + j * 3 + 1] * gln2_b[l * 3 + 1] +
                l1_w[l * 12 + j * 3 + 2] * gln2_b[l * 3 + 2] + l1_b[l * 4 + j];
        }
        else if (s < 28) v = l2_w[l * 12 + (s - 16)];
        else if (s < 31) v = 0.f;                        // l2_b folded into N2bF
        else if (s < 34) v = gln3_w[l * 3 + (s - 31)];
        else if (s < 37) v = gln3_b[l * 3 + (s - 34)];
        fst[l][s] = v;
    }
    __syncthreads();

    // ---- persistent pinned weights (all scalar)
    float Wsq[NL_][6][3], Bsq[NL_][6];      // q (QS-scaled) + k rows
    float Wvp[NL_][3][3], Bvp[NL_][3];      // folded value path
    float Bso[NL_][3];
    float N1w[NL_][3], N1bF[NL_][3];        // N1bF = gln1_b + Bco
    float N2w[NL_][3], N2bF[NL_][3];        // N2bF = gln2_b + l2_b
    float wcu[NL_][3];
    float swcu[NL_];
    float cbb[NL_];
    float cvp[NL_][3];

    #pragma unroll
    for (int l = 0; l < NL_; ++l) {
        #pragma unroll
        for (int r = 0; r < 6; ++r) {
            float sc = (r < 3) ? QS : 1.0f;
            Bsq[l][r] = sa_qkv_b[l * 9 + r] * sc;
            #pragma unroll
            for (int c = 0; c < 3; ++c) Wsq[l][r][c] = sa_qkv_w[l * 27 + r * 3 + c] * sc;
        }
        // Wvp = Wso·Wv, Bvp = Wso·Bv
        #pragma unroll
        for (int r = 0; r < 3; ++r) {
            float w0 = sa_out_w[l * 9 + r * 3 + 0];
            float w1 = sa_out_w[l * 9 + r * 3 + 1];
            float w2 = sa_out_w[l * 9 + r * 3 + 2];
            Bvp[l][r] = w0 * sa_qkv_b[l * 9 + 6] + w1 * sa_qkv_b[l * 9 + 7] + w2 * sa_qkv_b[l * 9 + 8];
            #pragma unroll
            for (int c = 0; c < 3; ++c)
                Wvp[l][r][c] = w0 * sa_qkv_w[l * 27 + 6 * 3 + c] +
                               w1 * sa_qkv_w[l * 27 + 7 * 3 + c] +
                               w2 * sa_qkv_w[l * 27 + 8 * 3 + c];
        }
        #pragma unroll
        for (int r = 0; r < 3; ++r) {
            Bso[l][r]  = sa_out_b[l * 3 + r];
            N1w[l][r]  = gln1_w[l * 3 + r];
            N1bF[l][r] = gln1_b[l * 3 + r] + ca_out_b[l * 3 + r];
            N2w[l][r]  = gln2_w[l * 3 + r];
            N2bF[l][r] = gln2_b[l * 3 + r] + l2_b[l * 3 + r];
        }
    }

    // ---- cross-attn K/V per lane + query-side folds (LN1 folded in)
    float m0 = mem[(b * S_ + lane) * DD_ + 0];
    float m1 = mem[(b * S_ + lane) * DD_ + 1];
    float m2 = mem[(b * S_ + lane) * DD_ + 2];

    #pragma unroll
    for (int l = 0; l < NL_; ++l) {
        float ck[3], cv[3], cuv[3];
        #pragma unroll
        for (int r = 0; r < 3; ++r) {
            ck[r] = ca_qkv_w[l * 27 + (3 + r) * 3 + 0] * m0 +
                    ca_qkv_w[l * 27 + (3 + r) * 3 + 1] * m1 +
                    ca_qkv_w[l * 27 + (3 + r) * 3 + 2] * m2 + ca_qkv_b[l * 9 + 3 + r];
            cv[r] = ca_qkv_w[l * 27 + (6 + r) * 3 + 0] * m0 +
                    ca_qkv_w[l * 27 + (6 + r) * 3 + 1] * m1 +
                    ca_qkv_w[l * 27 + (6 + r) * 3 + 2] * m2 + ca_qkv_b[l * 9 + 6 + r];
        }
        #pragma unroll
        for (int s = 0; s < 3; ++s)
            cuv[s] = QS * (ca_qkv_w[l * 27 + 0 + s] * ck[0] +
                           ca_qkv_w[l * 27 + 3 + s] * ck[1] +
                           ca_qkv_w[l * 27 + 6 + s] * ck[2]);
        float cbv = QS * (ca_qkv_b[l * 9 + 0] * ck[0] +
                          ca_qkv_b[l * 9 + 1] * ck[1] +
                          ca_qkv_b[l * 9 + 2] * ck[2]);
        #pragma unroll
        for (int r = 0; r < 3; ++r)
            cvp[l][r] = ca_out_w[l * 9 + r * 3 + 0] * cv[0] +
                        ca_out_w[l * 9 + r * 3 + 1] * cv[1] +
                        ca_out_w[l * 9 + r * 3 + 2] * cv[2];
        // cbb uses TRUE gln1_b (score path), not the N1bF fold
        #pragma unroll
        for (int r = 0; r < 3; ++r) wcu[l][r] = cuv[r] * N1w[l][r];
        swcu[l] = wcu[l][0] + wcu[l][1] + wcu[l][2];
        cbb[l]  = cbv + cuv[0] * gln1_b[l * 3 + 0] + cuv[1] * gln1_b[l * 3 + 1]
                      + cuv[2] * gln1_b[l * 3 + 2];
    }

    // ---- pin the chain-critical persistent set (all scalar floats)
    #pragma unroll
    for (int l = 0; l < NL_; ++l) {
        #pragma unroll
        for (int r = 0; r < 6; ++r) {
            PIN(Bsq[l][r]);
            #pragma unroll
            for (int c = 0; c < 3; ++c) PIN(Wsq[l][r][c]);
        }
        PIN(swcu[l]); PIN(cbb[l]);
        #pragma unroll
        for (int r = 0; r < 3; ++r) {
            PIN(Bvp[l][r]); PIN(Bso[l][r]);
            PIN(N1w[l][r]); PIN(N1bF[l][r]); PIN(N2w[l][r]); PIN(N2bF[l][r]);
            PIN(wcu[l][r]); PIN(cvp[l][r]);
            #pragma unroll
            for (int c = 0; c < 3; ++c) PIN(Wvp[l][r][c]);
        }
    }

    // self-attn KV cache: lane j owns position j (sv holds Wso-transformed v')
    float sk[NL_][3] = {{0.f}}, sv[NL_][3] = {{0.f}};

    if (lane < 3) out[(b * S_ + 0) * 5 + lane] = 0.f;

    float y0 = 0.f, y1 = 0.f, y2 = 0.f;

    auto run_range = [&](int ibeg, int iend, auto nstc) {
        constexpr int NST = decltype(nstc)::value;
        constexpr int RL = (NST == 4) ? 15 : (NST == 5) ? 31 : 63;
        for (int i = ibeg; i < iend; ++i) {
            float msa = (lane <= i) ? 0.f : -1.0e30f;
            bool isme = (lane == i);
            #pragma unroll
            for (int l = 0; l < NL_; ++l) {
                // ---- FF-tail weights: ds_reads issued at layer top, PINned late
                float wv[40];
                {
                    const float4* fp = (const float4*)fst[l];
                    #pragma unroll
                    for (int k = 0; k < 10; ++k) {
                        float4 t4 = fp[k];
                        wv[4 * k + 0] = t4.x; wv[4 * k + 1] = t4.y;
                        wv[4 * k + 2] = t4.z; wv[4 * k + 3] = t4.w;
                    }
                }

                // ---- causal self-attention (q pre-scaled by QS; vp via Wvp fold)
                float q[3], kn[3], vp[3];
                #pragma unroll
                for (int r = 0; r < 3; ++r) {
                    kn[r] = fmaf(Wsq[l][3 + r][0], y0, fmaf(Wsq[l][3 + r][1], y1, fmaf(Wsq[l][3 + r][2], y2, Bsq[l][3 + r])));
                    q[r]  = fmaf(Wsq[l][r][0], y0, fmaf(Wsq[l][r][1], y1, fmaf(Wsq[l][r][2], y2, Bsq[l][r])));
                    vp[r] = fmaf(Wvp[l][r][0], y0, fmaf(Wvp[l][r][1], y1, fmaf(Wvp[l][r][2], y2, Bvp[l][r])));
                }
                if (isme) {
                    #pragma unroll
                    for (int r = 0; r < 3; ++r) { sk[l][r] = kn[r]; sv[l][r] = vp[r]; }
                }
                float sc = fmaf(q[0], sk[l][0], fmaf(q[1], sk[l][1], fmaf(q[2], sk[l][2], msa)));
                float e = __builtin_amdgcn_exp2f(sc);
                float se = e;
                float sa0 = e * sv[l][0];
                float sa1 = e * sv[l][1];
                float sa2 = e * sv[l][2];
                red16_4(se, sa0, sa1, sa2);
                if constexpr (NST >= 5) dpp4<0x142>(se, sa0, sa1, sa2);
                if constexpr (NST >= 6) dpp4<0x143>(se, sa0, sa1, sa2);
                float es = rlane<RL>(se);
                float S0 = rlane<RL>(sa0), S1 = rlane<RL>(sa1), S2 = rlane<RL>(sa2);
                // scale-invariant LN input: z = yb*es + S (no rcp on chain)
                float yb0 = y0 + Bso[l][0], yb1 = y1 + Bso[l][1], yb2 = y2 + Bso[l][2];
                float z0 = fmaf(yb0, es, S0), z1 = fmaf(yb1, es, S1), z2v = fmaf(yb2, es, S2);
                float ee = es * es;

                // ---- LN1 + folded CA score (rstd on chain; yc off-chain)
                float s1m = (z0 + z1) + z2v;
                float mu = s1m * (1.0f / 3.0f);
                float zw = fmaf(z0, wcu[l][0], fmaf(z1, wcu[l][1], z2v * wcu[l][2]));
                float inner = fmaf(-mu, swcu[l], zw);
                float s2m = fmaf(z0, z0, fmaf(z1, z1, z2v * z2v));
                float vpe = fmaf(s2m, (1.0f / 3.0f), fmaf(-mu, mu, 1e-5f * ee));
                float rstd1 = __builtin_amdgcn_rsqf(vpe);
                float sc2 = fmaf(rstd1, inner, cbb[l]);
                float e2 = __builtin_amdgcn_exp2f(sc2);
                float ce = e2;
                float ca0 = e2 * cvp[l][0];
                float ca1 = e2 * cvp[l][1];
                float ca2 = e2 * cvp[l][2];
                red16_4(ce, ca0, ca1, ca2);
                dpp4<0x142>(ce, ca0, ca1, ca2);
                dpp4<0x143>(ce, ca0, ca1, ca2);
                // yc = LN1-out + Bco directly via N1bF fold (off CA-reduce path)
                float yc0 = fmaf(z0 - mu, rstd1 * N1w[l][0], N1bF[l][0]);
                float yc1 = fmaf(z1 - mu, rstd1 * N1w[l][1], N1bF[l][1]);
                float yc2 = fmaf(z2v - mu, rstd1 * N1w[l][2], N1bF[l][2]);
                float cs = rlane<63>(ce);
                float C0 = rlane<63>(ca0), C1 = rlane<63>(ca1), C2 = rlane<63>(ca2);
                // scale-invariant again: g = yc*ce + C
                float g0 = fmaf(yc0, cs, C0), g1 = fmaf(yc1, cs, C1), g2 = fmaf(yc2, cs, C2);
                float cee = cs * cs;

                // ---- LN2 + folded FF1 (rstd2 on chain; yf off-chain)
                float t1m = (g0 + g1) + g2;
                float mu2 = t1m * (1.0f / 3.0f);
                float c20 = g0 - mu2, c21 = g1 - mu2, c22 = g2 - mu2;
                float t2m = fmaf(g0, g0, fmaf(g1, g1, g2 * g2));
                float vpe2 = fmaf(t2m, (1.0f / 3.0f), fmaf(-mu2, mu2, 1e-5f * cee));
                float rstd2 = __builtin_amdgcn_rsqf(vpe2);
                #pragma unroll
                for (int k = 0; k < 37; ++k) PIN(wv[k]);
                float d0 = fmaf(wv[0], c20, fmaf(wv[1],  c21, wv[2]  * c22));
                float d1 = fmaf(wv[3], c20, fmaf(wv[4],  c21, wv[5]  * c22));
                float d2 = fmaf(wv[6], c20, fmaf(wv[7],  c21, wv[8]  * c22));
                float d3 = fmaf(wv[9], c20, fmaf(wv[10], c21, wv[11] * c22));
                float h0 = fmaxf(fmaf(rstd2, d0, wv[12]), 0.f);
                float h1 = fmaxf(fmaf(rstd2, d1, wv[13]), 0.f);
                float h2 = fmaxf(fmaf(rstd2, d2, wv[14]), 0.f);
                float h3 = fmaxf(fmaf(rstd2, d3, wv[15]), 0.f);
                // yf = LN2-out + l2_b directly via N2bF fold
                float yf0 = fmaf(c20, rstd2 * N2w[l][0], N2bF[l][0]);
                float yf1 = fmaf(c21, rstd2 * N2w[l][1], N2bF[l][1]);
                float yf2 = fmaf(c22, rstd2 * N2w[l][2], N2bF[l][2]);
                float f0 = fmaf(wv[16], h0, fmaf(wv[17], h1, fmaf(wv[18], h2, fmaf(wv[19], h3, yf0))));
                float f1 = fmaf(wv[20], h0, fmaf(wv[21], h1, fmaf(wv[22], h2, fmaf(wv[23], h3, yf1))));
                float f2 = fmaf(wv[24], h0, fmaf(wv[25], h1, fmaf(wv[26], h2, fmaf(wv[27], h3, yf2))));
                ln3e(f0, f1, f2,
                     wv[31], wv[32], wv[33], wv[34], wv[35], wv[36],
                     y0, y1, y2);
            }
            if (lane == 0) {
                out[(b * S_ + i + 1) * 5 + 0] = y0;
                out[(b * S_ + i + 1) * 5 + 1] = y1;
                out[(b * S_ + i + 1) * 5 + 2] = y2;
            }
        }
    };

    run_range(0, 15, IC<4>{});
    run_range(15, 31, IC<5>{});
    run_range(31, S_ - 1, IC<6>{});
}

// ---------------------------------------------------------------------------
extern "C" void kernel_launch(void* const* d_in, const int* in_sizes, int n_in,
                              void* d_out, int out_size, void* d_ws, size_t ws_size,
                              hipStream_t stream) {
    const float* src  = (const float*)d_in[0];
    const float* wemb = (const float*)d_in[1];
    const float* semb = (const float*)d_in[2];

    float* mem = (float*)d_ws;           // [B,S,3] scratch
    float* out = (float*)d_out;          // [B,S,5]

    enc_kernel<<<B_, 512, 0, stream>>>(
        src, wemb, semb,
        (const float*)d_in[3],  (const float*)d_in[4],
        (const float*)d_in[5],  (const float*)d_in[6],
        (const float*)d_in[7],  (const float*)d_in[8],
        (const float*)d_in[9],  (const float*)d_in[10],
        (const float*)d_in[11], (const float*)d_in[12],
        (const float*)d_in[13], (const float*)d_in[14],
        (const float*)d_in[15], (const float*)d_in[16],
        (const float*)d_in[17], (const float*)d_in[18],
        mem, out);

    dec_kernel<<<B_, 64, 0, stream>>>(
        mem,
        (const float*)d_in[19], (const float*)d_in[20],
        (const float*)d_in[21], (const float*)d_in[22],
        (const float*)d_in[23], (const float*)d_in[24],
        (const float*)d_in[25], (const float*)d_in[26],
        (const float*)d_in[27], (const float*)d_in[28],
        (const float*)d_in[29], (const float*)d_in[30],
        (const float*)d_in[31], (const float*)d_in[32],
        (const float*)d_in[33], (const float*)d_in[34],
        (const float*)d_in[35], (const float*)d_in[36],
        out);
}